// Round 4
// baseline (262.458 us; speedup 1.0000x reference)
//
#include <hip/hip_runtime.h>
#include <hip/hip_bf16.h>

#define HID 1024
#define NHEADS 16
#define HDIM 64
#define SEQ 2048
#define NTOK 4096

typedef __attribute__((ext_vector_type(8))) short short8;
typedef __attribute__((ext_vector_type(4))) float f32x4;
typedef unsigned short ush;

__device__ __forceinline__ ush f2bf(float f) {
    unsigned int u = __float_as_uint(f);
    u = (u + 0x7fffu + ((u >> 16) & 1u)) >> 16;
    return (ush)u;
}
__device__ __forceinline__ void async_copy16(const void* g, void* l) {
    __builtin_amdgcn_global_load_lds(
        (const __attribute__((address_space(1))) void*)g,
        (__attribute__((address_space(3))) void*)l, 16, 0, 0);
}
#define SBAR()  __builtin_amdgcn_s_barrier()
#define SCHED() __builtin_amdgcn_sched_barrier(0)

// ---------------- Kernel 0: f32 -> bf16 convert (X and stacked W) ----------------
__global__ __launch_bounds__(256) void cvt_kernel(
    const float* __restrict__ X, const float* __restrict__ Wq,
    const float* __restrict__ Wk, const float* __restrict__ Wg,
    ush* __restrict__ Xbf, ush* __restrict__ Wbf)
{
    long i = (long)blockIdx.x * 256 + threadIdx.x;   // 917504 vec8 groups
    const float* src; ush* dst; long j;
    if (i < 524288)      { src = X;  dst = Xbf;           j = i; }
    else if (i < 655360) { src = Wq; dst = Wbf;           j = i - 524288; }
    else if (i < 786432) { src = Wk; dst = Wbf + 1048576; j = i - 655360; }
    else                 { src = Wg; dst = Wbf + 2097152; j = i - 786432; }
    float4 a = *reinterpret_cast<const float4*>(src + j * 8);
    float4 b = *reinterpret_cast<const float4*>(src + j * 8 + 4);
    short8 o;
    o[0] = (short)f2bf(a.x); o[1] = (short)f2bf(a.y);
    o[2] = (short)f2bf(a.z); o[3] = (short)f2bf(a.w);
    o[4] = (short)f2bf(b.x); o[5] = (short)f2bf(b.y);
    o[6] = (short)f2bf(b.z); o[7] = (short)f2bf(b.w);
    *reinterpret_cast<short8*>(dst + j * 8) = o;
}

// ---------------- Kernel 1: fused projection GEMM (N = 3072 = Q|K|gate) ----------------
__global__ __launch_bounds__(256, 2) void proj_kernel(
    const ush* __restrict__ Xbf, const ush* __restrict__ Wbf,
    const float* __restrict__ bgp,
    ush* __restrict__ Qbf, ush* __restrict__ Kbf,
    float* __restrict__ gate)
{
    __shared__ __align__(16) ush As[2][128 * 64];
    __shared__ __align__(16) ush Bs[2][128 * 64];

    const int lin = blockIdx.y * 24 + blockIdx.x;   // 768 blocks, 768%8==0
    const int swz = (lin & 7) * 96 + (lin >> 3);
    const int n0 = (swz % 24) * 128;
    const int m0 = (swz / 24) * 128;
    const int tid = threadIdx.x, lane = tid & 63, wv = tid >> 6;
    const int wm = wv >> 1, wn = wv & 1;
    const int l16 = lane & 15, lq = lane >> 4;
    const int lrow = lane >> 3, lc = lane & 7;
    const int scU = lc ^ lrow;
    const int u0 = lq ^ (l16 & 7);

    f32x4 acc[4][4];
    #pragma unroll
    for (int i = 0; i < 4; i++)
        #pragma unroll
        for (int j = 0; j < 4; j++)
            #pragma unroll
            for (int r = 0; r < 4; r++) acc[i][j][r] = 0.0f;

    const ush* gA = Xbf + (long)m0 * HID;
    const ush* gB = Wbf + (long)n0 * HID;

    auto stage = [&](int k0, int bu) {
        #pragma unroll
        for (int c = 0; c < 4; ++c) {
            int chunk = wv * 4 + c;
            int row = chunk * 8 + lrow;
            async_copy16(gA + (long)row * HID + k0 + scU * 8, &As[bu][chunk * 512]);
            async_copy16(gB + (long)row * HID + k0 + scU * 8, &Bs[bu][chunk * 512]);
        }
    };

    stage(0, 0);
    stage(64, 1);

    for (int k = 0; k < 16; ++k) {
        const int cur = k & 1;
        if (k == 15) asm volatile("s_waitcnt vmcnt(0)" ::: "memory");
        else         asm volatile("s_waitcnt vmcnt(8)" ::: "memory");
        SCHED();
        SBAR(); SCHED();
        #pragma unroll
        for (int ks = 0; ks < 2; ++ks) {
            const int uo = (ks ? (u0 ^ 4) : u0) * 8;
            short8 a[4], b[4];
            #pragma unroll
            for (int mf = 0; mf < 4; mf++)
                a[mf] = *reinterpret_cast<const short8*>(&As[cur][(wm * 64 + mf * 16 + l16) * 64 + uo]);
            #pragma unroll
            for (int nf = 0; nf < 4; nf++)
                b[nf] = *reinterpret_cast<const short8*>(&Bs[cur][(wn * 64 + nf * 16 + l16) * 64 + uo]);
            #pragma unroll
            for (int mf = 0; mf < 4; mf++)
                #pragma unroll
                for (int nf = 0; nf < 4; nf++)
                    acc[mf][nf] = __builtin_amdgcn_mfma_f32_16x16x32_bf16(a[mf], b[nf], acc[mf][nf], 0, 0, 0);
        }
        SBAR(); SCHED();
        if (k < 14) stage((k + 2) * 64, cur);
    }

    const int z = n0 >> 10;   // 0=Q, 1=K, 2=gate
    #pragma unroll
    for (int mf = 0; mf < 4; mf++)
        #pragma unroll
        for (int nf = 0; nf < 4; nf++) {
            int row = m0 + wm * 64 + mf * 16 + lq * 4;
            int col = (n0 + wn * 64 + nf * 16 + l16) & 1023;
            #pragma unroll
            for (int r = 0; r < 4; r++) {
                float v = acc[mf][nf][r];
                long idx = (long)(row + r) * HID + col;
                if (z == 0)      Qbf[idx] = f2bf(v * 0.18033688011112042f); // 0.125*log2e
                else if (z == 1) Kbf[idx] = f2bf(v);
                else             gate[idx] = 1.0f / (1.0f + __expf(-(v + bgp[col])));
            }
        }
}

// ---------------- Kernel 1.5: per-head V transpose VtG[bh][d][s] ----------------
__global__ __launch_bounds__(256) void vt_kernel(
    const ush* __restrict__ Kbf, ush* __restrict__ VtG)
{
    __shared__ __align__(16) ush tile[64][72];
    const int s0 = blockIdx.x * 64;
    const int h  = blockIdx.y;
    const int b  = blockIdx.z;
    const int bh = b * NHEADS + h;
    const int tb = b * SEQ;
    const int colbase = h * HDIM;
    const int tid = threadIdx.x;
    #pragma unroll
    for (int i = 0; i < 2; ++i) {
        int idx = i * 256 + tid;
        int row = idx >> 3, c8 = (idx & 7) * 8;
        *reinterpret_cast<uint4*>(&tile[row][c8]) =
            *reinterpret_cast<const uint4*>(&Kbf[(long)(tb + s0 + row) * HID + colbase + c8]);
    }
    __syncthreads();
    #pragma unroll
    for (int i = 0; i < 2; ++i) {
        int idx = i * 256 + tid;
        int d = idx >> 3, c8 = (idx & 7) * 8;
        ush tmp[8];
        #pragma unroll
        for (int j = 0; j < 8; ++j) tmp[j] = tile[c8 + j][d];
        *reinterpret_cast<uint4*>(&VtG[((long)bh * HDIM + d) * SEQ + s0 + c8]) =
            *reinterpret_cast<uint4*>(tmp);
    }
}

// ---------------- Kernel 2: fused attention (swapped QK layout) ----------------
// acc = S[q][k]: col=k=l16, row=q=lq*4+r. Lane-local denom per k; float4 attn
// stores; cvt_pk+ds_write_b64 At staging (wave-private -> no mid barrier).
__global__ __launch_bounds__(256, 2) void attn_kernel(
    const ush* __restrict__ Qbf,
    const ush* __restrict__ Kbf,
    const ush* __restrict__ VtG,
    float* __restrict__ outp,      // [4096][1024], holds gate on entry
    float* __restrict__ attnp)     // [32][2048][2048]
{
    __shared__ __align__(16) ush Ks[128 * 64];
    __shared__ __align__(16) ush Qs[3][64 * 64];
    __shared__ __align__(16) ush Vt[2][64 * 64];
    __shared__ __align__(16) ush At[128][72];

    const int lin = (blockIdx.z * 16 + blockIdx.y) * 16 + blockIdx.x; // 512, %8==0
    const int swzb = (lin & 7) * 64 + (lin >> 3);
    const int kblk = swzb & 15;
    const int h    = (swzb >> 4) & 15;
    const int b    = swzb >> 8;
    const int bh   = b * NHEADS + h;
    const int tb   = b * SEQ;
    const int colbase = h * HDIM;
    const int tid  = threadIdx.x;
    const int lane = tid & 63;
    const int wv   = tid >> 6;
    const int l16  = lane & 15, lq = lane >> 4;
    const int lrow = lane >> 3, lc = lane & 7;
    const int scU  = lc ^ lrow;
    const int u0   = lq ^ (l16 & 7);

    const ush* Krow = Kbf + (long)(tb + kblk * 128) * HID + colbase;

    auto stageK = [&]() {
        #pragma unroll
        for (int c = 0; c < 4; ++c) {
            int chunk = wv * 4 + c;
            int row = chunk * 8 + lrow;
            async_copy16(Krow + (long)row * HID + scU * 8, &Ks[chunk * 512]);
        }
    };
    auto stageQ = [&](int q0, int bu) {
        #pragma unroll
        for (int c = 0; c < 2; ++c) {
            int chunk = wv * 2 + c;
            int row = chunk * 8 + lrow;
            async_copy16(Qbf + (long)(tb + q0 + row) * HID + colbase + scU * 8,
                         &Qs[bu][chunk * 512]);
        }
    };
    auto stageV = [&](int q0, int bu) {
        #pragma unroll
        for (int c = 0; c < 2; ++c) {
            int chunk = wv * 2 + c;
            int row = chunk * 8 + lrow;           // row = d
            async_copy16(VtG + ((long)bh * HDIM + row) * SEQ + q0 + scU * 8,
                         &Vt[bu][chunk * 512]);
        }
    };

    // ======== pass A: lane-local exp2 sums per k ========
    stageK();
    stageQ(0, 0);
    stageQ(64, 1);

    float ps[2] = {0.0f, 0.0f};

    for (int i = 0; i < 32; ++i) {
        if (i == 31) asm volatile("s_waitcnt vmcnt(0)" ::: "memory");
        else         asm volatile("s_waitcnt vmcnt(2)" ::: "memory");
        SCHED();
        SBAR(); SCHED();
        if (i < 30) stageQ((i + 2) * 64, (i + 2) % 3);

        f32x4 acc[4][2];
        #pragma unroll
        for (int x = 0; x < 4; x++)
            #pragma unroll
            for (int y = 0; y < 2; y++)
                #pragma unroll
                for (int r = 0; r < 4; r++) acc[x][y][r] = 0.0f;

        const ush* Qb = &Qs[i % 3][0];
        #pragma unroll
        for (int ks = 0; ks < 2; ks++) {
            const int uo = (ks ? (u0 ^ 4) : u0) * 8;
            short8 aq[4], bk[2];
            #pragma unroll
            for (int mf = 0; mf < 4; mf++)
                aq[mf] = *reinterpret_cast<const short8*>(&Qb[(mf * 16 + l16) * 64 + uo]);
            #pragma unroll
            for (int nf = 0; nf < 2; nf++)
                bk[nf] = *reinterpret_cast<const short8*>(&Ks[(wv * 32 + nf * 16 + l16) * 64 + uo]);
            #pragma unroll
            for (int mf = 0; mf < 4; mf++)
                #pragma unroll
                for (int nf = 0; nf < 2; nf++)
                    acc[mf][nf] = __builtin_amdgcn_mfma_f32_16x16x32_bf16(aq[mf], bk[nf], acc[mf][nf], 0, 0, 0);
        }

        #pragma unroll
        for (int nf = 0; nf < 2; nf++) {
            float s = 0.0f;
            #pragma unroll
            for (int mf = 0; mf < 4; mf++)
                #pragma unroll
                for (int r = 0; r < 4; r++)
                    s += exp2f(acc[mf][nf][r]);
            ps[nf] += s;
        }

        SBAR(); SCHED();
    }

    // denom: sum over the 4 lq lanes holding the same k (l16)
    float inv_r[2];
    #pragma unroll
    for (int nf = 0; nf < 2; nf++) {
        float v = ps[nf];
        v += __shfl_xor(v, 16);
        v += __shfl_xor(v, 32);
        inv_r[nf] = 1.0f / v;
    }

    f32x4 octx[2][4];
    #pragma unroll
    for (int x = 0; x < 2; x++)
        #pragma unroll
        for (int y = 0; y < 4; y++)
            #pragma unroll
            for (int r = 0; r < 4; r++) octx[x][y][r] = 0.0f;

    // ======== pass B ========
    stageQ(0, 0); stageV(0, 0);
    stageQ(64, 1); stageV(64, 1);

    for (int i = 0; i < 32; ++i) {
        const int q0 = i << 6;
        if (i == 0)       asm volatile("s_waitcnt vmcnt(4)"  ::: "memory");
        else if (i == 31) asm volatile("s_waitcnt vmcnt(8)"  ::: "memory");
        else              asm volatile("s_waitcnt vmcnt(12)" ::: "memory");
        SCHED();
        SBAR(); SCHED();
        if (i < 30) stageQ((i + 2) * 64, (i + 2) % 3);

        f32x4 acc[4][2];
        #pragma unroll
        for (int x = 0; x < 4; x++)
            #pragma unroll
            for (int y = 0; y < 2; y++)
                #pragma unroll
                for (int r = 0; r < 4; r++) acc[x][y][r] = 0.0f;

        const ush* Qb = &Qs[i % 3][0];
        #pragma unroll
        for (int ks = 0; ks < 2; ks++) {
            const int uo = (ks ? (u0 ^ 4) : u0) * 8;
            short8 aq[4], bk[2];
            #pragma unroll
            for (int mf = 0; mf < 4; mf++)
                aq[mf] = *reinterpret_cast<const short8*>(&Qb[(mf * 16 + l16) * 64 + uo]);
            #pragma unroll
            for (int nf = 0; nf < 2; nf++)
                bk[nf] = *reinterpret_cast<const short8*>(&Ks[(wv * 32 + nf * 16 + l16) * 64 + uo]);
            #pragma unroll
            for (int mf = 0; mf < 4; mf++)
                #pragma unroll
                for (int nf = 0; nf < 2; nf++)
                    acc[mf][nf] = __builtin_amdgcn_mfma_f32_16x16x32_bf16(aq[mf], bk[nf], acc[mf][nf], 0, 0, 0);
        }

        // softmax: lane holds 4 consecutive q for its k-row
        #pragma unroll
        for (int nf = 0; nf < 2; nf++) {
            const int krl = wv * 32 + nf * 16 + l16;
            const long rowbase = ((long)bh * SEQ + kblk * 128 + krl) * SEQ + q0;
            const float inv = inv_r[nf];
            #pragma unroll
            for (int mf = 0; mf < 4; mf++) {
                const int qc = mf * 16 + lq * 4;
                float p0 = exp2f(acc[mf][nf][0]) * inv;
                float p1 = exp2f(acc[mf][nf][1]) * inv;
                float p2 = exp2f(acc[mf][nf][2]) * inv;
                float p3 = exp2f(acc[mf][nf][3]) * inv;
                float4 st; st.x = p0; st.y = p1; st.z = p2; st.w = p3;
                *reinterpret_cast<float4*>(attnp + rowbase + qc) = st;
                unsigned int w0, w1;
                asm volatile("v_cvt_pk_bf16_f32 %0, %1, %2" : "=v"(w0) : "v"(p0), "v"(p1));
                asm volatile("v_cvt_pk_bf16_f32 %0, %1, %2" : "=v"(w1) : "v"(p2), "v"(p3));
                *reinterpret_cast<uint2*>(&At[krl][qc]) = make_uint2(w0, w1);
            }
        }

        // At is wave-private (each wave reads only its own 32 k-rows): no barrier,
        // just drain LDS writes before the reads.
        asm volatile("s_waitcnt lgkmcnt(0)" ::: "memory");
        SCHED();

        // PV: ctx[k][d] += P[k][q] * Vt[d][q]
        #pragma unroll
        for (int ks = 0; ks < 2; ks++) {
            const int uo = (ks ? (u0 ^ 4) : u0) * 8;
            short8 a[2], bv[4];
            #pragma unroll
            for (int mf = 0; mf < 2; mf++)
                a[mf] = *reinterpret_cast<const short8*>(&At[wv * 32 + mf * 16 + l16][ks * 32 + lq * 8]);
            #pragma unroll
            for (int nf = 0; nf < 4; nf++)
                bv[nf] = *reinterpret_cast<const short8*>(&Vt[i & 1][(nf * 16 + l16) * 64 + uo]);
            #pragma unroll
            for (int mf = 0; mf < 2; mf++)
                #pragma unroll
                for (int nf = 0; nf < 4; nf++)
                    octx[mf][nf] = __builtin_amdgcn_mfma_f32_16x16x32_bf16(a[mf], bv[nf], octx[mf][nf], 0, 0, 0);
        }

        SBAR(); SCHED();
        if (i < 30) stageV((i + 2) * 64, i & 1);
    }

    // epilogue: out = gate * ctx
    #pragma unroll
    for (int mf = 0; mf < 2; mf++)
        #pragma unroll
        for (int nf = 0; nf < 4; nf++) {
            int row = tb + kblk * 128 + wv * 32 + mf * 16 + lq * 4;
            int col = colbase + nf * 16 + l16;
            #pragma unroll
            for (int r = 0; r < 4; r++) {
                long idx = (long)(row + r) * HID + col;
                outp[idx] = outp[idx] * octx[mf][nf][r];
            }
        }
}

extern "C" void kernel_launch(void* const* d_in, const int* in_sizes, int n_in,
                              void* d_out, int out_size, void* d_ws, size_t ws_size,
                              hipStream_t stream)
{
    const float* X  = (const float*)d_in[0];
    const float* Wq = (const float*)d_in[1];
    const float* Wk = (const float*)d_in[2];
    const float* Wg = (const float*)d_in[3];
    const float* bg = (const float*)d_in[4];

    float* outp  = (float*)d_out;
    float* attnp = outp + (long)NTOK * HID;

    ush* Qbf = (ush*)d_ws;
    ush* Kbf = Qbf + (long)NTOK * HID;
    ush* VtG = Kbf + (long)NTOK * HID;

    ush* Xbf = (ush*)(outp + 134742016L);
    ush* Wbf = Xbf + (long)NTOK * HID;

    cvt_kernel<<<3584, 256, 0, stream>>>(X, Wq, Wk, Wg, Xbf, Wbf);
    proj_kernel<<<dim3(24, 32), 256, 0, stream>>>(Xbf, Wbf, bg, Qbf, Kbf, outp);
    vt_kernel<<<dim3(32, 16, 2), 256, 0, stream>>>(Kbf, VtG);
    attn_kernel<<<dim3(16, 16, 2), 256, 0, stream>>>(Qbf, Kbf, VtG, outp, attnp);
}

// Round 6
// 224.569 us; speedup vs baseline: 1.1687x; 1.1687x over previous
//
#include <hip/hip_runtime.h>
#include <hip/hip_bf16.h>

#define HID 1024
#define NHEADS 16
#define HDIM 64
#define SEQ 2048
#define NTOK 4096

typedef __attribute__((ext_vector_type(8))) short short8;
typedef __attribute__((ext_vector_type(4))) float f32x4;
typedef unsigned short ush;

__device__ __forceinline__ ush f2bf(float f) {
    unsigned int u = __float_as_uint(f);
    u = (u + 0x7fffu + ((u >> 16) & 1u)) >> 16;
    return (ush)u;
}
__device__ __forceinline__ void async_copy16(const void* g, void* l) {
    __builtin_amdgcn_global_load_lds(
        (const __attribute__((address_space(1))) void*)g,
        (__attribute__((address_space(3))) void*)l, 16, 0, 0);
}
#define SBAR()  __builtin_amdgcn_s_barrier()
#define SCHED() __builtin_amdgcn_sched_barrier(0)

// ---------------- Kernel 0: f32 -> bf16 convert (X and stacked W) ----------------
__global__ __launch_bounds__(256) void cvt_kernel(
    const float* __restrict__ X, const float* __restrict__ Wq,
    const float* __restrict__ Wk, const float* __restrict__ Wg,
    ush* __restrict__ Xbf, ush* __restrict__ Wbf)
{
    long i = (long)blockIdx.x * 256 + threadIdx.x;   // 917504 vec8 groups
    const float* src; ush* dst; long j;
    if (i < 524288)      { src = X;  dst = Xbf;           j = i; }
    else if (i < 655360) { src = Wq; dst = Wbf;           j = i - 524288; }
    else if (i < 786432) { src = Wk; dst = Wbf + 1048576; j = i - 655360; }
    else                 { src = Wg; dst = Wbf + 2097152; j = i - 786432; }
    float4 a = *reinterpret_cast<const float4*>(src + j * 8);
    float4 b = *reinterpret_cast<const float4*>(src + j * 8 + 4);
    short8 o;
    o[0] = (short)f2bf(a.x); o[1] = (short)f2bf(a.y);
    o[2] = (short)f2bf(a.z); o[3] = (short)f2bf(a.w);
    o[4] = (short)f2bf(b.x); o[5] = (short)f2bf(b.y);
    o[6] = (short)f2bf(b.z); o[7] = (short)f2bf(b.w);
    *reinterpret_cast<short8*>(dst + j * 8) = o;
}

// ---------------- Kernel 1: fused projection GEMM (N = 3072 = Q|K|gate) ----------------
__global__ __launch_bounds__(256, 2) void proj_kernel(
    const ush* __restrict__ Xbf, const ush* __restrict__ Wbf,
    const float* __restrict__ bgp,
    ush* __restrict__ Qbf, ush* __restrict__ Kbf,
    float* __restrict__ gate)
{
    __shared__ __align__(16) ush As[2][128 * 64];
    __shared__ __align__(16) ush Bs[2][128 * 64];

    const int lin = blockIdx.y * 24 + blockIdx.x;   // 768 blocks, 768%8==0
    const int swz = (lin & 7) * 96 + (lin >> 3);
    const int n0 = (swz % 24) * 128;
    const int m0 = (swz / 24) * 128;
    const int tid = threadIdx.x, lane = tid & 63, wv = tid >> 6;
    const int wm = wv >> 1, wn = wv & 1;
    const int l16 = lane & 15, lq = lane >> 4;
    const int lrow = lane >> 3, lc = lane & 7;
    const int scU = lc ^ lrow;
    const int u0 = lq ^ (l16 & 7);

    f32x4 acc[4][4];
    #pragma unroll
    for (int i = 0; i < 4; i++)
        #pragma unroll
        for (int j = 0; j < 4; j++)
            #pragma unroll
            for (int r = 0; r < 4; r++) acc[i][j][r] = 0.0f;

    const ush* gA = Xbf + (long)m0 * HID;
    const ush* gB = Wbf + (long)n0 * HID;

    auto stage = [&](int k0, int bu) {
        #pragma unroll
        for (int c = 0; c < 4; ++c) {
            int chunk = wv * 4 + c;
            int row = chunk * 8 + lrow;
            async_copy16(gA + (long)row * HID + k0 + scU * 8, &As[bu][chunk * 512]);
            async_copy16(gB + (long)row * HID + k0 + scU * 8, &Bs[bu][chunk * 512]);
        }
    };

    stage(0, 0);
    stage(64, 1);

    for (int k = 0; k < 16; ++k) {
        const int cur = k & 1;
        if (k == 15) asm volatile("s_waitcnt vmcnt(0)" ::: "memory");
        else         asm volatile("s_waitcnt vmcnt(8)" ::: "memory");
        SCHED();
        SBAR(); SCHED();
        #pragma unroll
        for (int ks = 0; ks < 2; ++ks) {
            const int uo = (ks ? (u0 ^ 4) : u0) * 8;
            short8 a[4], b[4];
            #pragma unroll
            for (int mf = 0; mf < 4; mf++)
                a[mf] = *reinterpret_cast<const short8*>(&As[cur][(wm * 64 + mf * 16 + l16) * 64 + uo]);
            #pragma unroll
            for (int nf = 0; nf < 4; nf++)
                b[nf] = *reinterpret_cast<const short8*>(&Bs[cur][(wn * 64 + nf * 16 + l16) * 64 + uo]);
            #pragma unroll
            for (int mf = 0; mf < 4; mf++)
                #pragma unroll
                for (int nf = 0; nf < 4; nf++)
                    acc[mf][nf] = __builtin_amdgcn_mfma_f32_16x16x32_bf16(a[mf], b[nf], acc[mf][nf], 0, 0, 0);
        }
        SBAR(); SCHED();
        if (k < 14) stage((k + 2) * 64, cur);
    }

    const int z = n0 >> 10;   // 0=Q, 1=K, 2=gate
    #pragma unroll
    for (int mf = 0; mf < 4; mf++)
        #pragma unroll
        for (int nf = 0; nf < 4; nf++) {
            int row = m0 + wm * 64 + mf * 16 + lq * 4;
            int col = (n0 + wn * 64 + nf * 16 + l16) & 1023;
            #pragma unroll
            for (int r = 0; r < 4; r++) {
                float v = acc[mf][nf][r];
                long idx = (long)(row + r) * HID + col;
                if (z == 0)      Qbf[idx] = f2bf(v * 0.18033688011112042f); // 0.125*log2e
                else if (z == 1) Kbf[idx] = f2bf(v);
                else {
                    float gv = 1.0f / (1.0f + __expf(-(v + bgp[col])));
                    __builtin_nontemporal_store(gv, &gate[idx]);   // streamed; read much later
                }
            }
        }
}

// ---------------- Kernel 1.5: per-head V transpose VtG[bh][d][s] ----------------
__global__ __launch_bounds__(256) void vt_kernel(
    const ush* __restrict__ Kbf, ush* __restrict__ VtG)
{
    __shared__ __align__(16) ush tile[64][72];
    const int s0 = blockIdx.x * 64;
    const int h  = blockIdx.y;
    const int b  = blockIdx.z;
    const int bh = b * NHEADS + h;
    const int tb = b * SEQ;
    const int colbase = h * HDIM;
    const int tid = threadIdx.x;
    #pragma unroll
    for (int i = 0; i < 2; ++i) {
        int idx = i * 256 + tid;
        int row = idx >> 3, c8 = (idx & 7) * 8;
        *reinterpret_cast<uint4*>(&tile[row][c8]) =
            *reinterpret_cast<const uint4*>(&Kbf[(long)(tb + s0 + row) * HID + colbase + c8]);
    }
    __syncthreads();
    #pragma unroll
    for (int i = 0; i < 2; ++i) {
        int idx = i * 256 + tid;
        int d = idx >> 3, c8 = (idx & 7) * 8;
        ush tmp[8];
        #pragma unroll
        for (int j = 0; j < 8; ++j) tmp[j] = tile[c8 + j][d];
        *reinterpret_cast<uint4*>(&VtG[((long)bh * HDIM + d) * SEQ + s0 + c8]) =
            *reinterpret_cast<uint4*>(tmp);
    }
}

// ---------------- Kernel 2: fused attention (swapped QK layout) ----------------
// Pass B stores attnp from the At LDS tile: 4 rows x 256B contiguous segments
// per store instr, nontemporal (don't thrash L2 for Q/V re-reads).
__global__ __launch_bounds__(256, 2) void attn_kernel(
    const ush* __restrict__ Qbf,
    const ush* __restrict__ Kbf,
    const ush* __restrict__ VtG,
    float* __restrict__ outp,      // [4096][1024], holds gate on entry
    float* __restrict__ attnp)     // [32][2048][2048]
{
    __shared__ __align__(16) ush Ks[128 * 64];
    __shared__ __align__(16) ush Qs[3][64 * 64];
    __shared__ __align__(16) ush Vt[2][64 * 64];
    __shared__ __align__(16) ush At[128][72];

    const int lin = (blockIdx.z * 16 + blockIdx.y) * 16 + blockIdx.x; // 512, %8==0
    const int swzb = (lin & 7) * 64 + (lin >> 3);
    const int kblk = swzb & 15;
    const int h    = (swzb >> 4) & 15;
    const int b    = swzb >> 8;
    const int bh   = b * NHEADS + h;
    const int tb   = b * SEQ;
    const int colbase = h * HDIM;
    const int tid  = threadIdx.x;
    const int lane = tid & 63;
    const int wv   = tid >> 6;
    const int l16  = lane & 15, lq = lane >> 4;
    const int lrow = lane >> 3, lc = lane & 7;
    const int scU  = lc ^ lrow;
    const int u0   = lq ^ (l16 & 7);

    const ush* Krow = Kbf + (long)(tb + kblk * 128) * HID + colbase;

    auto stageK = [&]() {
        #pragma unroll
        for (int c = 0; c < 4; ++c) {
            int chunk = wv * 4 + c;
            int row = chunk * 8 + lrow;
            async_copy16(Krow + (long)row * HID + scU * 8, &Ks[chunk * 512]);
        }
    };
    auto stageQ = [&](int q0, int bu) {
        #pragma unroll
        for (int c = 0; c < 2; ++c) {
            int chunk = wv * 2 + c;
            int row = chunk * 8 + lrow;
            async_copy16(Qbf + (long)(tb + q0 + row) * HID + colbase + scU * 8,
                         &Qs[bu][chunk * 512]);
        }
    };
    auto stageV = [&](int q0, int bu) {
        #pragma unroll
        for (int c = 0; c < 2; ++c) {
            int chunk = wv * 2 + c;
            int row = chunk * 8 + lrow;           // row = d
            async_copy16(VtG + ((long)bh * HDIM + row) * SEQ + q0 + scU * 8,
                         &Vt[bu][chunk * 512]);
        }
    };

    // ======== pass A: lane-local exp2 sums per k ========
    stageK();
    stageQ(0, 0);
    stageQ(64, 1);

    float ps[2] = {0.0f, 0.0f};

    for (int i = 0; i < 32; ++i) {
        if (i == 31) asm volatile("s_waitcnt vmcnt(0)" ::: "memory");
        else         asm volatile("s_waitcnt vmcnt(2)" ::: "memory");
        SCHED();
        SBAR(); SCHED();
        if (i < 30) stageQ((i + 2) * 64, (i + 2) % 3);

        f32x4 acc[4][2];
        #pragma unroll
        for (int x = 0; x < 4; x++)
            #pragma unroll
            for (int y = 0; y < 2; y++)
                #pragma unroll
                for (int r = 0; r < 4; r++) acc[x][y][r] = 0.0f;

        const ush* Qb = &Qs[i % 3][0];
        #pragma unroll
        for (int ks = 0; ks < 2; ks++) {
            const int uo = (ks ? (u0 ^ 4) : u0) * 8;
            short8 aq[4], bk[2];
            #pragma unroll
            for (int mf = 0; mf < 4; mf++)
                aq[mf] = *reinterpret_cast<const short8*>(&Qb[(mf * 16 + l16) * 64 + uo]);
            #pragma unroll
            for (int nf = 0; nf < 2; nf++)
                bk[nf] = *reinterpret_cast<const short8*>(&Ks[(wv * 32 + nf * 16 + l16) * 64 + uo]);
            #pragma unroll
            for (int mf = 0; mf < 4; mf++)
                #pragma unroll
                for (int nf = 0; nf < 2; nf++)
                    acc[mf][nf] = __builtin_amdgcn_mfma_f32_16x16x32_bf16(aq[mf], bk[nf], acc[mf][nf], 0, 0, 0);
        }

        #pragma unroll
        for (int nf = 0; nf < 2; nf++) {
            float s = 0.0f;
            #pragma unroll
            for (int mf = 0; mf < 4; mf++)
                #pragma unroll
                for (int r = 0; r < 4; r++)
                    s += exp2f(acc[mf][nf][r]);
            ps[nf] += s;
        }

        SBAR(); SCHED();
    }

    // denom: sum over the 4 lq lanes holding the same k (l16)
    float inv_r[2];
    #pragma unroll
    for (int nf = 0; nf < 2; nf++) {
        float v = ps[nf];
        v += __shfl_xor(v, 16);
        v += __shfl_xor(v, 32);
        inv_r[nf] = 1.0f / v;
    }

    f32x4 octx[2][4];
    #pragma unroll
    for (int x = 0; x < 2; x++)
        #pragma unroll
        for (int y = 0; y < 4; y++)
            #pragma unroll
            for (int r = 0; r < 4; r++) octx[x][y][r] = 0.0f;

    // ======== pass B ========
    stageQ(0, 0); stageV(0, 0);
    stageQ(64, 1); stageV(64, 1);

    for (int i = 0; i < 32; ++i) {
        const int q0 = i << 6;
        if (i == 0)       asm volatile("s_waitcnt vmcnt(4)"  ::: "memory");
        else if (i == 31) asm volatile("s_waitcnt vmcnt(8)"  ::: "memory");
        else              asm volatile("s_waitcnt vmcnt(12)" ::: "memory");
        SCHED();
        SBAR(); SCHED();
        if (i < 30) stageQ((i + 2) * 64, (i + 2) % 3);

        f32x4 acc[4][2];
        #pragma unroll
        for (int x = 0; x < 4; x++)
            #pragma unroll
            for (int y = 0; y < 2; y++)
                #pragma unroll
                for (int r = 0; r < 4; r++) acc[x][y][r] = 0.0f;

        const ush* Qb = &Qs[i % 3][0];
        #pragma unroll
        for (int ks = 0; ks < 2; ks++) {
            const int uo = (ks ? (u0 ^ 4) : u0) * 8;
            short8 aq[4], bk[2];
            #pragma unroll
            for (int mf = 0; mf < 4; mf++)
                aq[mf] = *reinterpret_cast<const short8*>(&Qb[(mf * 16 + l16) * 64 + uo]);
            #pragma unroll
            for (int nf = 0; nf < 2; nf++)
                bk[nf] = *reinterpret_cast<const short8*>(&Ks[(wv * 32 + nf * 16 + l16) * 64 + uo]);
            #pragma unroll
            for (int mf = 0; mf < 4; mf++)
                #pragma unroll
                for (int nf = 0; nf < 2; nf++)
                    acc[mf][nf] = __builtin_amdgcn_mfma_f32_16x16x32_bf16(aq[mf], bk[nf], acc[mf][nf], 0, 0, 0);
        }

        // softmax -> bf16 P into wave-private At rows
        #pragma unroll
        for (int nf = 0; nf < 2; nf++) {
            const int krl = wv * 32 + nf * 16 + l16;
            const float inv = inv_r[nf];
            #pragma unroll
            for (int mf = 0; mf < 4; mf++) {
                const int qc = mf * 16 + lq * 4;
                float p0 = exp2f(acc[mf][nf][0]) * inv;
                float p1 = exp2f(acc[mf][nf][1]) * inv;
                float p2 = exp2f(acc[mf][nf][2]) * inv;
                float p3 = exp2f(acc[mf][nf][3]) * inv;
                unsigned int w0, w1;
                asm volatile("v_cvt_pk_bf16_f32 %0, %1, %2" : "=v"(w0) : "v"(p0), "v"(p1));
                asm volatile("v_cvt_pk_bf16_f32 %0, %1, %2" : "=v"(w1) : "v"(p2), "v"(p3));
                *reinterpret_cast<uint2*>(&At[krl][qc]) = make_uint2(w0, w1);
            }
        }

        // At is wave-private; drain LDS writes before reading back.
        asm volatile("s_waitcnt lgkmcnt(0)" ::: "memory");
        SCHED();

        // attnp stores from At: per instr 4 rows x 256B contiguous, nontemporal
        {
            const int rlo = lane >> 4;            // 0..3
            const int qc  = (lane & 15) * 4;      // 0..60
            #pragma unroll
            for (int j = 0; j < 8; ++j) {
                const int rl = wv * 32 + j * 4 + rlo;
                uint2 w = *reinterpret_cast<const uint2*>(&At[rl][qc]);
                f32x4 st;
                st[0] = __uint_as_float(w.x << 16);
                st[1] = __uint_as_float(w.x & 0xffff0000u);
                st[2] = __uint_as_float(w.y << 16);
                st[3] = __uint_as_float(w.y & 0xffff0000u);
                __builtin_nontemporal_store(st,
                    reinterpret_cast<f32x4*>(attnp + ((long)bh * SEQ + kblk * 128 + rl) * SEQ + q0 + qc));
            }
        }

        // PV: ctx[k][d] += P[k][q] * Vt[d][q]
        #pragma unroll
        for (int ks = 0; ks < 2; ks++) {
            const int uo = (ks ? (u0 ^ 4) : u0) * 8;
            short8 a[2], bv[4];
            #pragma unroll
            for (int mf = 0; mf < 2; mf++)
                a[mf] = *reinterpret_cast<const short8*>(&At[wv * 32 + mf * 16 + l16][ks * 32 + lq * 8]);
            #pragma unroll
            for (int nf = 0; nf < 4; nf++)
                bv[nf] = *reinterpret_cast<const short8*>(&Vt[i & 1][(nf * 16 + l16) * 64 + uo]);
            #pragma unroll
            for (int mf = 0; mf < 2; mf++)
                #pragma unroll
                for (int nf = 0; nf < 4; nf++)
                    octx[mf][nf] = __builtin_amdgcn_mfma_f32_16x16x32_bf16(a[mf], bv[nf], octx[mf][nf], 0, 0, 0);
        }

        SBAR(); SCHED();
        if (i < 30) stageV((i + 2) * 64, i & 1);
    }

    // epilogue: out = gate * ctx (nontemporal out)
    #pragma unroll
    for (int mf = 0; mf < 2; mf++)
        #pragma unroll
        for (int nf = 0; nf < 4; nf++) {
            int row = tb + kblk * 128 + wv * 32 + mf * 16 + lq * 4;
            int col = colbase + nf * 16 + l16;
            #pragma unroll
            for (int r = 0; r < 4; r++) {
                long idx = (long)(row + r) * HID + col;
                float o = outp[idx] * octx[mf][nf][r];
                __builtin_nontemporal_store(o, &outp[idx]);
            }
        }
}

extern "C" void kernel_launch(void* const* d_in, const int* in_sizes, int n_in,
                              void* d_out, int out_size, void* d_ws, size_t ws_size,
                              hipStream_t stream)
{
    const float* X  = (const float*)d_in[0];
    const float* Wq = (const float*)d_in[1];
    const float* Wk = (const float*)d_in[2];
    const float* Wg = (const float*)d_in[3];
    const float* bg = (const float*)d_in[4];

    float* outp  = (float*)d_out;
    float* attnp = outp + (long)NTOK * HID;

    ush* Qbf = (ush*)d_ws;
    ush* Kbf = Qbf + (long)NTOK * HID;
    ush* VtG = Kbf + (long)NTOK * HID;

    ush* Xbf = (ush*)(outp + 134742016L);
    ush* Wbf = Xbf + (long)NTOK * HID;

    cvt_kernel<<<3584, 256, 0, stream>>>(X, Wq, Wk, Wg, Xbf, Wbf);
    proj_kernel<<<dim3(24, 32), 256, 0, stream>>>(Xbf, Wbf, bg, Qbf, Kbf, outp);
    vt_kernel<<<dim3(32, 16, 2), 256, 0, stream>>>(Kbf, VtG);
    attn_kernel<<<dim3(16, 16, 2), 256, 0, stream>>>(Qbf, Kbf, VtG, outp, attnp);
}

// Round 7
// 223.454 us; speedup vs baseline: 1.1746x; 1.0050x over previous
//
#include <hip/hip_runtime.h>
#include <hip/hip_bf16.h>

#define HID 1024
#define NHEADS 16
#define HDIM 64
#define SEQ 2048
#define NTOK 4096

typedef __attribute__((ext_vector_type(8))) short short8;
typedef __attribute__((ext_vector_type(4))) float f32x4;
typedef unsigned short ush;

__device__ __forceinline__ ush f2bf(float f) {
    unsigned int u = __float_as_uint(f);
    u = (u + 0x7fffu + ((u >> 16) & 1u)) >> 16;
    return (ush)u;
}
__device__ __forceinline__ void async_copy16(const void* g, void* l) {
    __builtin_amdgcn_global_load_lds(
        (const __attribute__((address_space(1))) void*)g,
        (__attribute__((address_space(3))) void*)l, 16, 0, 0);
}
#define SBAR()  __builtin_amdgcn_s_barrier()
#define SCHED() __builtin_amdgcn_sched_barrier(0)

// ---------------- Kernel 0: f32 -> bf16 convert (X and stacked W) ----------------
__global__ __launch_bounds__(256) void cvt_kernel(
    const float* __restrict__ X, const float* __restrict__ Wq,
    const float* __restrict__ Wk, const float* __restrict__ Wg,
    ush* __restrict__ Xbf, ush* __restrict__ Wbf)
{
    long i = (long)blockIdx.x * 256 + threadIdx.x;   // 917504 vec8 groups
    const float* src; ush* dst; long j;
    if (i < 524288)      { src = X;  dst = Xbf;           j = i; }
    else if (i < 655360) { src = Wq; dst = Wbf;           j = i - 524288; }
    else if (i < 786432) { src = Wk; dst = Wbf + 1048576; j = i - 655360; }
    else                 { src = Wg; dst = Wbf + 2097152; j = i - 786432; }
    float4 a = *reinterpret_cast<const float4*>(src + j * 8);
    float4 b = *reinterpret_cast<const float4*>(src + j * 8 + 4);
    short8 o;
    o[0] = (short)f2bf(a.x); o[1] = (short)f2bf(a.y);
    o[2] = (short)f2bf(a.z); o[3] = (short)f2bf(a.w);
    o[4] = (short)f2bf(b.x); o[5] = (short)f2bf(b.y);
    o[6] = (short)f2bf(b.z); o[7] = (short)f2bf(b.w);
    *reinterpret_cast<short8*>(dst + j * 8) = o;
}

// ---------------- Kernel 1: fused projection GEMM (N = 3072 = Q|K|gate) ----------------
__global__ __launch_bounds__(256, 2) void proj_kernel(
    const ush* __restrict__ Xbf, const ush* __restrict__ Wbf,
    const float* __restrict__ bgp,
    ush* __restrict__ Qbf, ush* __restrict__ Kbf,
    float* __restrict__ gate)
{
    __shared__ __align__(16) ush As[2][128 * 64];
    __shared__ __align__(16) ush Bs[2][128 * 64];

    const int lin = blockIdx.y * 24 + blockIdx.x;   // 768 blocks, 768%8==0
    const int swz = (lin & 7) * 96 + (lin >> 3);
    const int n0 = (swz % 24) * 128;
    const int m0 = (swz / 24) * 128;
    const int tid = threadIdx.x, lane = tid & 63, wv = tid >> 6;
    const int wm = wv >> 1, wn = wv & 1;
    const int l16 = lane & 15, lq = lane >> 4;
    const int lrow = lane >> 3, lc = lane & 7;
    const int scU = lc ^ lrow;
    const int u0 = lq ^ (l16 & 7);

    f32x4 acc[4][4];
    #pragma unroll
    for (int i = 0; i < 4; i++)
        #pragma unroll
        for (int j = 0; j < 4; j++)
            #pragma unroll
            for (int r = 0; r < 4; r++) acc[i][j][r] = 0.0f;

    const ush* gA = Xbf + (long)m0 * HID;
    const ush* gB = Wbf + (long)n0 * HID;

    auto stage = [&](int k0, int bu) {
        #pragma unroll
        for (int c = 0; c < 4; ++c) {
            int chunk = wv * 4 + c;
            int row = chunk * 8 + lrow;
            async_copy16(gA + (long)row * HID + k0 + scU * 8, &As[bu][chunk * 512]);
            async_copy16(gB + (long)row * HID + k0 + scU * 8, &Bs[bu][chunk * 512]);
        }
    };

    stage(0, 0);
    stage(64, 1);

    for (int k = 0; k < 16; ++k) {
        const int cur = k & 1;
        if (k == 15) asm volatile("s_waitcnt vmcnt(0)" ::: "memory");
        else         asm volatile("s_waitcnt vmcnt(8)" ::: "memory");
        SCHED();
        SBAR(); SCHED();
        #pragma unroll
        for (int ks = 0; ks < 2; ++ks) {
            const int uo = (ks ? (u0 ^ 4) : u0) * 8;
            short8 a[4], b[4];
            #pragma unroll
            for (int mf = 0; mf < 4; mf++)
                a[mf] = *reinterpret_cast<const short8*>(&As[cur][(wm * 64 + mf * 16 + l16) * 64 + uo]);
            #pragma unroll
            for (int nf = 0; nf < 4; nf++)
                b[nf] = *reinterpret_cast<const short8*>(&Bs[cur][(wn * 64 + nf * 16 + l16) * 64 + uo]);
            #pragma unroll
            for (int mf = 0; mf < 4; mf++)
                #pragma unroll
                for (int nf = 0; nf < 4; nf++)
                    acc[mf][nf] = __builtin_amdgcn_mfma_f32_16x16x32_bf16(a[mf], b[nf], acc[mf][nf], 0, 0, 0);
        }
        SBAR(); SCHED();
        if (k < 14) stage((k + 2) * 64, cur);
    }

    const int z = n0 >> 10;   // 0=Q, 1=K, 2=gate
    #pragma unroll
    for (int mf = 0; mf < 4; mf++)
        #pragma unroll
        for (int nf = 0; nf < 4; nf++) {
            int row = m0 + wm * 64 + mf * 16 + lq * 4;
            int col = (n0 + wn * 64 + nf * 16 + l16) & 1023;
            #pragma unroll
            for (int r = 0; r < 4; r++) {
                float v = acc[mf][nf][r];
                long idx = (long)(row + r) * HID + col;
                if (z == 0)      Qbf[idx] = f2bf(v * 0.18033688011112042f); // 0.125*log2e
                else if (z == 1) Kbf[idx] = f2bf(v);
                else {
                    float gv = 1.0f / (1.0f + __expf(-(v + bgp[col])));
                    __builtin_nontemporal_store(gv, &gate[idx]);   // streamed; read much later
                }
            }
        }
}

// ---------------- Kernel 1.5: per-head V transpose VtG[bh][d][s] ----------------
__global__ __launch_bounds__(256) void vt_kernel(
    const ush* __restrict__ Kbf, ush* __restrict__ VtG)
{
    __shared__ __align__(16) ush tile[64][72];
    const int s0 = blockIdx.x * 64;
    const int h  = blockIdx.y;
    const int b  = blockIdx.z;
    const int bh = b * NHEADS + h;
    const int tb = b * SEQ;
    const int colbase = h * HDIM;
    const int tid = threadIdx.x;
    #pragma unroll
    for (int i = 0; i < 2; ++i) {
        int idx = i * 256 + tid;
        int row = idx >> 3, c8 = (idx & 7) * 8;
        *reinterpret_cast<uint4*>(&tile[row][c8]) =
            *reinterpret_cast<const uint4*>(&Kbf[(long)(tb + s0 + row) * HID + colbase + c8]);
    }
    __syncthreads();
    #pragma unroll
    for (int i = 0; i < 2; ++i) {
        int idx = i * 256 + tid;
        int d = idx >> 3, c8 = (idx & 7) * 8;
        ush tmp[8];
        #pragma unroll
        for (int j = 0; j < 8; ++j) tmp[j] = tile[c8 + j][d];
        *reinterpret_cast<uint4*>(&VtG[((long)bh * HDIM + d) * SEQ + s0 + c8]) =
            *reinterpret_cast<uint4*>(tmp);
    }
}

// ---------------- Kernel 2: fused attention (swapped QK layout) ----------------
// Pass B VMEM issue order per iter: Q-load, V-load, then stores LAST, with
// counted vmcnt(20) steady state -> stores get a 2-iteration drain window and
// loads never wait on store completion (in-order vmcnt retirement).
__global__ __launch_bounds__(256, 2) void attn_kernel(
    const ush* __restrict__ Qbf,
    const ush* __restrict__ Kbf,
    const ush* __restrict__ VtG,
    float* __restrict__ outp,      // [4096][1024], holds gate on entry
    float* __restrict__ attnp)     // [32][2048][2048]
{
    __shared__ __align__(16) ush Ks[128 * 64];
    __shared__ __align__(16) ush Qs[3][64 * 64];
    __shared__ __align__(16) ush Vt[2][64 * 64];
    __shared__ __align__(16) ush At[128][72];

    const int lin = (blockIdx.z * 16 + blockIdx.y) * 16 + blockIdx.x; // 512, %8==0
    const int swzb = (lin & 7) * 64 + (lin >> 3);
    const int kblk = swzb & 15;
    const int h    = (swzb >> 4) & 15;
    const int b    = swzb >> 8;
    const int bh   = b * NHEADS + h;
    const int tb   = b * SEQ;
    const int colbase = h * HDIM;
    const int tid  = threadIdx.x;
    const int lane = tid & 63;
    const int wv   = tid >> 6;
    const int l16  = lane & 15, lq = lane >> 4;
    const int lrow = lane >> 3, lc = lane & 7;
    const int scU  = lc ^ lrow;
    const int u0   = lq ^ (l16 & 7);

    const ush* Krow = Kbf + (long)(tb + kblk * 128) * HID + colbase;

    auto stageK = [&]() {
        #pragma unroll
        for (int c = 0; c < 4; ++c) {
            int chunk = wv * 4 + c;
            int row = chunk * 8 + lrow;
            async_copy16(Krow + (long)row * HID + scU * 8, &Ks[chunk * 512]);
        }
    };
    auto stageQ = [&](int q0, int bu) {
        #pragma unroll
        for (int c = 0; c < 2; ++c) {
            int chunk = wv * 2 + c;
            int row = chunk * 8 + lrow;
            async_copy16(Qbf + (long)(tb + q0 + row) * HID + colbase + scU * 8,
                         &Qs[bu][chunk * 512]);
        }
    };
    auto stageV = [&](int q0, int bu) {
        #pragma unroll
        for (int c = 0; c < 2; ++c) {
            int chunk = wv * 2 + c;
            int row = chunk * 8 + lrow;           // row = d
            async_copy16(VtG + ((long)bh * HDIM + row) * SEQ + q0 + scU * 8,
                         &Vt[bu][chunk * 512]);
        }
    };

    // ======== pass A: lane-local exp2 sums per k ========
    stageK();
    stageQ(0, 0);
    stageQ(64, 1);

    float ps[2] = {0.0f, 0.0f};

    for (int i = 0; i < 32; ++i) {
        if (i == 31) asm volatile("s_waitcnt vmcnt(0)" ::: "memory");
        else         asm volatile("s_waitcnt vmcnt(2)" ::: "memory");
        SCHED();
        SBAR(); SCHED();
        if (i < 30) stageQ((i + 2) * 64, (i + 2) % 3);

        f32x4 acc[4][2];
        #pragma unroll
        for (int x = 0; x < 4; x++)
            #pragma unroll
            for (int y = 0; y < 2; y++)
                #pragma unroll
                for (int r = 0; r < 4; r++) acc[x][y][r] = 0.0f;

        const ush* Qb = &Qs[i % 3][0];
        #pragma unroll
        for (int ks = 0; ks < 2; ks++) {
            const int uo = (ks ? (u0 ^ 4) : u0) * 8;
            short8 aq[4], bk[2];
            #pragma unroll
            for (int mf = 0; mf < 4; mf++)
                aq[mf] = *reinterpret_cast<const short8*>(&Qb[(mf * 16 + l16) * 64 + uo]);
            #pragma unroll
            for (int nf = 0; nf < 2; nf++)
                bk[nf] = *reinterpret_cast<const short8*>(&Ks[(wv * 32 + nf * 16 + l16) * 64 + uo]);
            #pragma unroll
            for (int mf = 0; mf < 4; mf++)
                #pragma unroll
                for (int nf = 0; nf < 2; nf++)
                    acc[mf][nf] = __builtin_amdgcn_mfma_f32_16x16x32_bf16(aq[mf], bk[nf], acc[mf][nf], 0, 0, 0);
        }

        #pragma unroll
        for (int nf = 0; nf < 2; nf++) {
            float s = 0.0f;
            #pragma unroll
            for (int mf = 0; mf < 4; mf++)
                #pragma unroll
                for (int r = 0; r < 4; r++)
                    s += exp2f(acc[mf][nf][r]);
            ps[nf] += s;
        }

        SBAR(); SCHED();
    }

    // denom: sum over the 4 lq lanes holding the same k (l16)
    float inv_r[2];
    #pragma unroll
    for (int nf = 0; nf < 2; nf++) {
        float v = ps[nf];
        v += __shfl_xor(v, 16);
        v += __shfl_xor(v, 32);
        inv_r[nf] = 1.0f / v;
    }

    f32x4 octx[2][4];
    #pragma unroll
    for (int x = 0; x < 2; x++)
        #pragma unroll
        for (int y = 0; y < 4; y++)
            #pragma unroll
            for (int r = 0; r < 4; r++) octx[x][y][r] = 0.0f;

    // ======== pass B ========
    stageQ(0, 0); stageV(0, 0);
    stageQ(64, 1); stageV(64, 1);

    for (int i = 0; i < 32; ++i) {
        const int q0 = i << 6;
        // in-order vmcnt: wait only up through V(i); stores from iters i-2/i-1
        // may remain in flight (steady state 20 = st8+Q2+V2+st8).
        if (i == 0)       asm volatile("s_waitcnt vmcnt(4)"  ::: "memory");
        else if (i == 1)  asm volatile("s_waitcnt vmcnt(12)" ::: "memory");
        else if (i == 31) asm volatile("s_waitcnt vmcnt(16)" ::: "memory");
        else              asm volatile("s_waitcnt vmcnt(20)" ::: "memory");
        SCHED();
        SBAR(); SCHED();
        if (i < 30) stageQ((i + 2) * 64, (i + 2) % 3);

        f32x4 acc[4][2];
        #pragma unroll
        for (int x = 0; x < 4; x++)
            #pragma unroll
            for (int y = 0; y < 2; y++)
                #pragma unroll
                for (int r = 0; r < 4; r++) acc[x][y][r] = 0.0f;

        const ush* Qb = &Qs[i % 3][0];
        #pragma unroll
        for (int ks = 0; ks < 2; ks++) {
            const int uo = (ks ? (u0 ^ 4) : u0) * 8;
            short8 aq[4], bk[2];
            #pragma unroll
            for (int mf = 0; mf < 4; mf++)
                aq[mf] = *reinterpret_cast<const short8*>(&Qb[(mf * 16 + l16) * 64 + uo]);
            #pragma unroll
            for (int nf = 0; nf < 2; nf++)
                bk[nf] = *reinterpret_cast<const short8*>(&Ks[(wv * 32 + nf * 16 + l16) * 64 + uo]);
            #pragma unroll
            for (int mf = 0; mf < 4; mf++)
                #pragma unroll
                for (int nf = 0; nf < 2; nf++)
                    acc[mf][nf] = __builtin_amdgcn_mfma_f32_16x16x32_bf16(aq[mf], bk[nf], acc[mf][nf], 0, 0, 0);
        }

        // softmax -> bf16 P into wave-private At rows
        #pragma unroll
        for (int nf = 0; nf < 2; nf++) {
            const int krl = wv * 32 + nf * 16 + l16;
            const float inv = inv_r[nf];
            #pragma unroll
            for (int mf = 0; mf < 4; mf++) {
                const int qc = mf * 16 + lq * 4;
                float p0 = exp2f(acc[mf][nf][0]) * inv;
                float p1 = exp2f(acc[mf][nf][1]) * inv;
                float p2 = exp2f(acc[mf][nf][2]) * inv;
                float p3 = exp2f(acc[mf][nf][3]) * inv;
                unsigned int w0, w1;
                asm volatile("v_cvt_pk_bf16_f32 %0, %1, %2" : "=v"(w0) : "v"(p0), "v"(p1));
                asm volatile("v_cvt_pk_bf16_f32 %0, %1, %2" : "=v"(w1) : "v"(p2), "v"(p3));
                *reinterpret_cast<uint2*>(&At[krl][qc]) = make_uint2(w0, w1);
            }
        }

        // drain At writes (wave-private), then pull store data into regs
        asm volatile("s_waitcnt lgkmcnt(0)" ::: "memory");
        SCHED();

        uint2 wreg[8];
        const int rlo = lane >> 4;            // 0..3
        const int qc  = (lane & 15) * 4;      // 0..60
        #pragma unroll
        for (int j = 0; j < 8; ++j)
            wreg[j] = *reinterpret_cast<const uint2*>(&At[wv * 32 + j * 4 + rlo][qc]);

        // PV: ctx[k][d] += P[k][q] * Vt[d][q]
        #pragma unroll
        for (int ks = 0; ks < 2; ks++) {
            const int uo = (ks ? (u0 ^ 4) : u0) * 8;
            short8 a[2], bv[4];
            #pragma unroll
            for (int mf = 0; mf < 2; mf++)
                a[mf] = *reinterpret_cast<const short8*>(&At[wv * 32 + mf * 16 + l16][ks * 32 + lq * 8]);
            #pragma unroll
            for (int nf = 0; nf < 4; nf++)
                bv[nf] = *reinterpret_cast<const short8*>(&Vt[i & 1][(nf * 16 + l16) * 64 + uo]);
            #pragma unroll
            for (int mf = 0; mf < 2; mf++)
                #pragma unroll
                for (int nf = 0; nf < 4; nf++)
                    octx[mf][nf] = __builtin_amdgcn_mfma_f32_16x16x32_bf16(a[mf], bv[nf], octx[mf][nf], 0, 0, 0);
        }

        SBAR(); SCHED();
        if (i < 30) stageV((i + 2) * 64, i & 1);

        // attn stores LAST: 4 rows x 256B contiguous per instr, nontemporal
        #pragma unroll
        for (int j = 0; j < 8; ++j) {
            const int rl = wv * 32 + j * 4 + rlo;
            f32x4 st;
            st[0] = __uint_as_float(wreg[j].x << 16);
            st[1] = __uint_as_float(wreg[j].x & 0xffff0000u);
            st[2] = __uint_as_float(wreg[j].y << 16);
            st[3] = __uint_as_float(wreg[j].y & 0xffff0000u);
            __builtin_nontemporal_store(st,
                reinterpret_cast<f32x4*>(attnp + ((long)bh * SEQ + kblk * 128 + rl) * SEQ + q0 + qc));
        }
    }

    // epilogue: out = gate * ctx (nontemporal in/out)
    #pragma unroll
    for (int mf = 0; mf < 2; mf++)
        #pragma unroll
        for (int nf = 0; nf < 4; nf++) {
            int row = tb + kblk * 128 + wv * 32 + mf * 16 + lq * 4;
            int col = colbase + nf * 16 + l16;
            #pragma unroll
            for (int r = 0; r < 4; r++) {
                long idx = (long)(row + r) * HID + col;
                float g = __builtin_nontemporal_load(&outp[idx]);
                __builtin_nontemporal_store(g * octx[mf][nf][r], &outp[idx]);
            }
        }
}

extern "C" void kernel_launch(void* const* d_in, const int* in_sizes, int n_in,
                              void* d_out, int out_size, void* d_ws, size_t ws_size,
                              hipStream_t stream)
{
    const float* X  = (const float*)d_in[0];
    const float* Wq = (const float*)d_in[1];
    const float* Wk = (const float*)d_in[2];
    const float* Wg = (const float*)d_in[3];
    const float* bg = (const float*)d_in[4];

    float* outp  = (float*)d_out;
    float* attnp = outp + (long)NTOK * HID;

    ush* Qbf = (ush*)d_ws;
    ush* Kbf = Qbf + (long)NTOK * HID;
    ush* VtG = Kbf + (long)NTOK * HID;

    ush* Xbf = (ush*)(outp + 134742016L);
    ush* Wbf = Xbf + (long)NTOK * HID;

    cvt_kernel<<<3584, 256, 0, stream>>>(X, Wq, Wk, Wg, Xbf, Wbf);
    proj_kernel<<<dim3(24, 32), 256, 0, stream>>>(Xbf, Wbf, bg, Qbf, Kbf, outp);
    vt_kernel<<<dim3(32, 16, 2), 256, 0, stream>>>(Kbf, VtG);
    attn_kernel<<<dim3(16, 16, 2), 256, 0, stream>>>(Qbf, Kbf, VtG, outp, attnp);
}

// Round 8
// 219.337 us; speedup vs baseline: 1.1966x; 1.0188x over previous
//
#include <hip/hip_runtime.h>
#include <hip/hip_bf16.h>

#define HID 1024
#define NHEADS 16
#define HDIM 64
#define SEQ 2048
#define NTOK 4096

typedef __attribute__((ext_vector_type(8))) short short8;
typedef __attribute__((ext_vector_type(4))) float f32x4;
typedef unsigned short ush;

__device__ __forceinline__ ush f2bf(float f) {
    unsigned int u = __float_as_uint(f);
    u = (u + 0x7fffu + ((u >> 16) & 1u)) >> 16;
    return (ush)u;
}
__device__ __forceinline__ void async_copy16(const void* g, void* l) {
    __builtin_amdgcn_global_load_lds(
        (const __attribute__((address_space(1))) void*)g,
        (__attribute__((address_space(3))) void*)l, 16, 0, 0);
}
#define SBAR()  __builtin_amdgcn_s_barrier()
#define SCHED() __builtin_amdgcn_sched_barrier(0)

// ---------------- Kernel 0: f32 -> bf16 convert (X and stacked W) ----------------
__global__ __launch_bounds__(256) void cvt_kernel(
    const float* __restrict__ X, const float* __restrict__ Wq,
    const float* __restrict__ Wk, const float* __restrict__ Wg,
    ush* __restrict__ Xbf, ush* __restrict__ Wbf)
{
    long i = (long)blockIdx.x * 256 + threadIdx.x;   // 917504 vec8 groups
    const float* src; ush* dst; long j;
    if (i < 524288)      { src = X;  dst = Xbf;           j = i; }
    else if (i < 655360) { src = Wq; dst = Wbf;           j = i - 524288; }
    else if (i < 786432) { src = Wk; dst = Wbf + 1048576; j = i - 655360; }
    else                 { src = Wg; dst = Wbf + 2097152; j = i - 786432; }
    float4 a = *reinterpret_cast<const float4*>(src + j * 8);
    float4 b = *reinterpret_cast<const float4*>(src + j * 8 + 4);
    short8 o;
    o[0] = (short)f2bf(a.x); o[1] = (short)f2bf(a.y);
    o[2] = (short)f2bf(a.z); o[3] = (short)f2bf(a.w);
    o[4] = (short)f2bf(b.x); o[5] = (short)f2bf(b.y);
    o[6] = (short)f2bf(b.z); o[7] = (short)f2bf(b.w);
    *reinterpret_cast<short8*>(dst + j * 8) = o;
}

// ---------------- Kernel 1: fused projection GEMM (N = 3072 = Q|K|gate) ----------------
// z==1 (K) additionally writes the per-head transposed copy VtG[bh][d][s]
// directly from acc regs (lane holds 4 consecutive s for fixed d).
__global__ __launch_bounds__(256, 2) void proj_kernel(
    const ush* __restrict__ Xbf, const ush* __restrict__ Wbf,
    const float* __restrict__ bgp,
    ush* __restrict__ Qbf, ush* __restrict__ Kbf,
    ush* __restrict__ VtG,
    float* __restrict__ gate)
{
    __shared__ __align__(16) ush As[2][128 * 64];
    __shared__ __align__(16) ush Bs[2][128 * 64];

    const int lin = blockIdx.y * 24 + blockIdx.x;   // 768 blocks, 768%8==0
    const int swz = (lin & 7) * 96 + (lin >> 3);
    const int n0 = (swz % 24) * 128;
    const int m0 = (swz / 24) * 128;
    const int tid = threadIdx.x, lane = tid & 63, wv = tid >> 6;
    const int wm = wv >> 1, wn = wv & 1;
    const int l16 = lane & 15, lq = lane >> 4;
    const int lrow = lane >> 3, lc = lane & 7;
    const int scU = lc ^ lrow;
    const int u0 = lq ^ (l16 & 7);

    f32x4 acc[4][4];
    #pragma unroll
    for (int i = 0; i < 4; i++)
        #pragma unroll
        for (int j = 0; j < 4; j++)
            #pragma unroll
            for (int r = 0; r < 4; r++) acc[i][j][r] = 0.0f;

    const ush* gA = Xbf + (long)m0 * HID;
    const ush* gB = Wbf + (long)n0 * HID;

    auto stage = [&](int k0, int bu) {
        #pragma unroll
        for (int c = 0; c < 4; ++c) {
            int chunk = wv * 4 + c;
            int row = chunk * 8 + lrow;
            async_copy16(gA + (long)row * HID + k0 + scU * 8, &As[bu][chunk * 512]);
            async_copy16(gB + (long)row * HID + k0 + scU * 8, &Bs[bu][chunk * 512]);
        }
    };

    stage(0, 0);
    stage(64, 1);

    for (int k = 0; k < 16; ++k) {
        const int cur = k & 1;
        if (k == 15) asm volatile("s_waitcnt vmcnt(0)" ::: "memory");
        else         asm volatile("s_waitcnt vmcnt(8)" ::: "memory");
        SCHED();
        SBAR(); SCHED();
        #pragma unroll
        for (int ks = 0; ks < 2; ++ks) {
            const int uo = (ks ? (u0 ^ 4) : u0) * 8;
            short8 a[4], b[4];
            #pragma unroll
            for (int mf = 0; mf < 4; mf++)
                a[mf] = *reinterpret_cast<const short8*>(&As[cur][(wm * 64 + mf * 16 + l16) * 64 + uo]);
            #pragma unroll
            for (int nf = 0; nf < 4; nf++)
                b[nf] = *reinterpret_cast<const short8*>(&Bs[cur][(wn * 64 + nf * 16 + l16) * 64 + uo]);
            #pragma unroll
            for (int mf = 0; mf < 4; mf++)
                #pragma unroll
                for (int nf = 0; nf < 4; nf++)
                    acc[mf][nf] = __builtin_amdgcn_mfma_f32_16x16x32_bf16(a[mf], b[nf], acc[mf][nf], 0, 0, 0);
        }
        SBAR(); SCHED();
        if (k < 14) stage((k + 2) * 64, cur);
    }

    const int z = n0 >> 10;   // 0=Q, 1=K, 2=gate
    #pragma unroll
    for (int mf = 0; mf < 4; mf++)
        #pragma unroll
        for (int nf = 0; nf < 4; nf++) {
            int row = m0 + wm * 64 + mf * 16 + lq * 4;
            int gcol = n0 + wn * 64 + nf * 16 + l16;
            int col = gcol & 1023;
            #pragma unroll
            for (int r = 0; r < 4; r++) {
                float v = acc[mf][nf][r];
                long idx = (long)(row + r) * HID + col;
                if (z == 0)      Qbf[idx] = f2bf(v * 0.18033688011112042f); // 0.125*log2e
                else if (z == 1) Kbf[idx] = f2bf(v);
                else {
                    float gv = 1.0f / (1.0f + __expf(-(v + bgp[col])));
                    __builtin_nontemporal_store(gv, &gate[idx]);
                }
            }
            if (z == 1) {
                // V-transpose write: 4 consecutive s for fixed (bh,d)
                int bb = row >> 11, s = row & 2047;
                int bh = bb * NHEADS + (col >> 6);
                int d  = col & 63;
                unsigned int w0, w1;
                asm volatile("v_cvt_pk_bf16_f32 %0, %1, %2" : "=v"(w0)
                             : "v"(acc[mf][nf][0]), "v"(acc[mf][nf][1]));
                asm volatile("v_cvt_pk_bf16_f32 %0, %1, %2" : "=v"(w1)
                             : "v"(acc[mf][nf][2]), "v"(acc[mf][nf][3]));
                *reinterpret_cast<uint2*>(&VtG[((long)bh * HDIM + d) * SEQ + s]) =
                    make_uint2(w0, w1);
            }
        }
}

// ---------------- Kernel 2: fused attention (swapped QK layout) ----------------
__global__ __launch_bounds__(256, 2) void attn_kernel(
    const ush* __restrict__ Qbf,
    const ush* __restrict__ Kbf,
    const ush* __restrict__ VtG,
    float* __restrict__ outp,      // [4096][1024], holds gate on entry
    float* __restrict__ attnp)     // [32][2048][2048]
{
    __shared__ __align__(16) ush Ks[128 * 64];
    // QsA: slots 0..2 = Q rotation (pass A & B); slot 3 (pass A only) aliases
    // the At region (pass B). At = QsA + 12288, [128][72].
    __shared__ __align__(16) ush QsA[3 * 4096 + 128 * 72];
    __shared__ __align__(16) ush Vt[2][64 * 64];

    ush (*At)[72] = reinterpret_cast<ush(*)[72]>(&QsA[12288]);

    const int lin = (blockIdx.z * 16 + blockIdx.y) * 16 + blockIdx.x; // 512, %8==0
    const int swzb = (lin & 7) * 64 + (lin >> 3);
    const int kblk = swzb & 15;
    const int h    = (swzb >> 4) & 15;
    const int b    = swzb >> 8;
    const int bh   = b * NHEADS + h;
    const int tb   = b * SEQ;
    const int colbase = h * HDIM;
    const int tid  = threadIdx.x;
    const int lane = tid & 63;
    const int wv   = tid >> 6;
    const int l16  = lane & 15, lq = lane >> 4;
    const int lrow = lane >> 3, lc = lane & 7;
    const int scU  = lc ^ lrow;
    const int u0   = lq ^ (l16 & 7);

    const ush* Krow = Kbf + (long)(tb + kblk * 128) * HID + colbase;

    auto stageK = [&]() {
        #pragma unroll
        for (int c = 0; c < 4; ++c) {
            int chunk = wv * 4 + c;
            int row = chunk * 8 + lrow;
            async_copy16(Krow + (long)row * HID + scU * 8, &Ks[chunk * 512]);
        }
    };
    auto stageQ = [&](int q0, int bu) {   // bu in 0..3
        #pragma unroll
        for (int c = 0; c < 2; ++c) {
            int chunk = wv * 2 + c;
            int row = chunk * 8 + lrow;
            async_copy16(Qbf + (long)(tb + q0 + row) * HID + colbase + scU * 8,
                         &QsA[bu * 4096 + chunk * 512]);
        }
    };
    auto stageV = [&](int q0, int bu) {
        #pragma unroll
        for (int c = 0; c < 2; ++c) {
            int chunk = wv * 2 + c;
            int row = chunk * 8 + lrow;           // row = d
            async_copy16(VtG + ((long)bh * HDIM + row) * SEQ + q0 + scU * 8,
                         &Vt[bu][chunk * 512]);
        }
    };

    // ======== pass A: lane-local exp2 sums per k (1 barrier/iter, 4-slot Q) ========
    stageK();
    stageQ(0, 0);
    stageQ(64, 1);

    float ps[2] = {0.0f, 0.0f};

    for (int i = 0; i < 32; ++i) {
        if (i >= 30) asm volatile("s_waitcnt vmcnt(0)" ::: "memory");
        else         asm volatile("s_waitcnt vmcnt(2)" ::: "memory");
        SCHED();
        SBAR(); SCHED();
        if (i < 30) stageQ((i + 2) * 64, (i + 2) & 3);

        f32x4 acc[4][2];
        #pragma unroll
        for (int x = 0; x < 4; x++)
            #pragma unroll
            for (int y = 0; y < 2; y++)
                #pragma unroll
                for (int r = 0; r < 4; r++) acc[x][y][r] = 0.0f;

        const ush* Qb = &QsA[(i & 3) * 4096];
        #pragma unroll
        for (int ks = 0; ks < 2; ks++) {
            const int uo = (ks ? (u0 ^ 4) : u0) * 8;
            short8 aq[4], bk[2];
            #pragma unroll
            for (int mf = 0; mf < 4; mf++)
                aq[mf] = *reinterpret_cast<const short8*>(&Qb[(mf * 16 + l16) * 64 + uo]);
            #pragma unroll
            for (int nf = 0; nf < 2; nf++)
                bk[nf] = *reinterpret_cast<const short8*>(&Ks[(wv * 32 + nf * 16 + l16) * 64 + uo]);
            #pragma unroll
            for (int mf = 0; mf < 4; mf++)
                #pragma unroll
                for (int nf = 0; nf < 2; nf++)
                    acc[mf][nf] = __builtin_amdgcn_mfma_f32_16x16x32_bf16(aq[mf], bk[nf], acc[mf][nf], 0, 0, 0);
        }

        #pragma unroll
        for (int nf = 0; nf < 2; nf++) {
            float s = 0.0f;
            #pragma unroll
            for (int mf = 0; mf < 4; mf++)
                #pragma unroll
                for (int r = 0; r < 4; r++)
                    s += exp2f(acc[mf][nf][r]);
            ps[nf] += s;
        }
    }

    // denom: sum over the 4 lq lanes holding the same k (l16)
    float inv_r[2];
    #pragma unroll
    for (int nf = 0; nf < 2; nf++) {
        float v = ps[nf];
        v += __shfl_xor(v, 16);
        v += __shfl_xor(v, 32);
        inv_r[nf] = 1.0f / v;
    }

    f32x4 octx[2][4];
    #pragma unroll
    for (int x = 0; x < 2; x++)
        #pragma unroll
        for (int y = 0; y < 4; y++)
            #pragma unroll
            for (int r = 0; r < 4; r++) octx[x][y][r] = 0.0f;

    // ======== pass B (3-slot Q rotation; slot 3 now serves as At) ========
    SBAR();   // ensure all waves done with pass A reads before At aliasing
    stageQ(0, 0); stageV(0, 0);
    stageQ(64, 1); stageV(64, 1);

    for (int i = 0; i < 32; ++i) {
        const int q0 = i << 6;
        if (i == 0)       asm volatile("s_waitcnt vmcnt(4)"  ::: "memory");
        else if (i == 1)  asm volatile("s_waitcnt vmcnt(12)" ::: "memory");
        else if (i == 31) asm volatile("s_waitcnt vmcnt(16)" ::: "memory");
        else              asm volatile("s_waitcnt vmcnt(20)" ::: "memory");
        SCHED();
        SBAR(); SCHED();
        if (i < 30) stageQ((i + 2) * 64, (i + 2) % 3);

        f32x4 acc[4][2];
        #pragma unroll
        for (int x = 0; x < 4; x++)
            #pragma unroll
            for (int y = 0; y < 2; y++)
                #pragma unroll
                for (int r = 0; r < 4; r++) acc[x][y][r] = 0.0f;

        const ush* Qb = &QsA[(i % 3) * 4096];
        #pragma unroll
        for (int ks = 0; ks < 2; ks++) {
            const int uo = (ks ? (u0 ^ 4) : u0) * 8;
            short8 aq[4], bk[2];
            #pragma unroll
            for (int mf = 0; mf < 4; mf++)
                aq[mf] = *reinterpret_cast<const short8*>(&Qb[(mf * 16 + l16) * 64 + uo]);
            #pragma unroll
            for (int nf = 0; nf < 2; nf++)
                bk[nf] = *reinterpret_cast<const short8*>(&Ks[(wv * 32 + nf * 16 + l16) * 64 + uo]);
            #pragma unroll
            for (int mf = 0; mf < 4; mf++)
                #pragma unroll
                for (int nf = 0; nf < 2; nf++)
                    acc[mf][nf] = __builtin_amdgcn_mfma_f32_16x16x32_bf16(aq[mf], bk[nf], acc[mf][nf], 0, 0, 0);
        }

        // softmax -> bf16 P into wave-private At rows
        #pragma unroll
        for (int nf = 0; nf < 2; nf++) {
            const int krl = wv * 32 + nf * 16 + l16;
            const float inv = inv_r[nf];
            #pragma unroll
            for (int mf = 0; mf < 4; mf++) {
                const int qc = mf * 16 + lq * 4;
                float p0 = exp2f(acc[mf][nf][0]) * inv;
                float p1 = exp2f(acc[mf][nf][1]) * inv;
                float p2 = exp2f(acc[mf][nf][2]) * inv;
                float p3 = exp2f(acc[mf][nf][3]) * inv;
                unsigned int w0, w1;
                asm volatile("v_cvt_pk_bf16_f32 %0, %1, %2" : "=v"(w0) : "v"(p0), "v"(p1));
                asm volatile("v_cvt_pk_bf16_f32 %0, %1, %2" : "=v"(w1) : "v"(p2), "v"(p3));
                *reinterpret_cast<uint2*>(&At[krl][qc]) = make_uint2(w0, w1);
            }
        }

        // drain At writes (wave-private), then pull store data into regs
        asm volatile("s_waitcnt lgkmcnt(0)" ::: "memory");
        SCHED();

        uint2 wreg[8];
        const int rlo = lane >> 4;            // 0..3
        const int qc  = (lane & 15) * 4;      // 0..60
        #pragma unroll
        for (int j = 0; j < 8; ++j)
            wreg[j] = *reinterpret_cast<const uint2*>(&At[wv * 32 + j * 4 + rlo][qc]);

        // PV: ctx[k][d] += P[k][q] * Vt[d][q]
        #pragma unroll
        for (int ks = 0; ks < 2; ks++) {
            const int uo = (ks ? (u0 ^ 4) : u0) * 8;
            short8 a[2], bv[4];
            #pragma unroll
            for (int mf = 0; mf < 2; mf++)
                a[mf] = *reinterpret_cast<const short8*>(&At[wv * 32 + mf * 16 + l16][ks * 32 + lq * 8]);
            #pragma unroll
            for (int nf = 0; nf < 4; nf++)
                bv[nf] = *reinterpret_cast<const short8*>(&Vt[i & 1][(nf * 16 + l16) * 64 + uo]);
            #pragma unroll
            for (int mf = 0; mf < 2; mf++)
                #pragma unroll
                for (int nf = 0; nf < 4; nf++)
                    octx[mf][nf] = __builtin_amdgcn_mfma_f32_16x16x32_bf16(a[mf], bv[nf], octx[mf][nf], 0, 0, 0);
        }

        SBAR(); SCHED();
        if (i < 30) stageV((i + 2) * 64, i & 1);

        // attn stores LAST: 4 rows x 256B contiguous per instr, nontemporal
        #pragma unroll
        for (int j = 0; j < 8; ++j) {
            const int rl = wv * 32 + j * 4 + rlo;
            f32x4 st;
            st[0] = __uint_as_float(wreg[j].x << 16);
            st[1] = __uint_as_float(wreg[j].x & 0xffff0000u);
            st[2] = __uint_as_float(wreg[j].y << 16);
            st[3] = __uint_as_float(wreg[j].y & 0xffff0000u);
            __builtin_nontemporal_store(st,
                reinterpret_cast<f32x4*>(attnp + ((long)bh * SEQ + kblk * 128 + rl) * SEQ + q0 + qc));
        }
    }

    // epilogue: out = gate * ctx (nontemporal in/out)
    #pragma unroll
    for (int mf = 0; mf < 2; mf++)
        #pragma unroll
        for (int nf = 0; nf < 4; nf++) {
            int row = tb + kblk * 128 + wv * 32 + mf * 16 + lq * 4;
            int col = colbase + nf * 16 + l16;
            #pragma unroll
            for (int r = 0; r < 4; r++) {
                long idx = (long)(row + r) * HID + col;
                float g = __builtin_nontemporal_load(&outp[idx]);
                __builtin_nontemporal_store(g * octx[mf][nf][r], &outp[idx]);
            }
        }
}

extern "C" void kernel_launch(void* const* d_in, const int* in_sizes, int n_in,
                              void* d_out, int out_size, void* d_ws, size_t ws_size,
                              hipStream_t stream)
{
    const float* X  = (const float*)d_in[0];
    const float* Wq = (const float*)d_in[1];
    const float* Wk = (const float*)d_in[2];
    const float* Wg = (const float*)d_in[3];
    const float* bg = (const float*)d_in[4];

    float* outp  = (float*)d_out;
    float* attnp = outp + (long)NTOK * HID;

    ush* Qbf = (ush*)d_ws;
    ush* Kbf = Qbf + (long)NTOK * HID;
    ush* VtG = Kbf + (long)NTOK * HID;

    ush* Xbf = (ush*)(outp + 134742016L);
    ush* Wbf = Xbf + (long)NTOK * HID;

    cvt_kernel<<<3584, 256, 0, stream>>>(X, Wq, Wk, Wg, Xbf, Wbf);
    proj_kernel<<<dim3(24, 32), 256, 0, stream>>>(Xbf, Wbf, bg, Qbf, Kbf, VtG, outp);
    attn_kernel<<<dim3(16, 16, 2), 256, 0, stream>>>(Qbf, Kbf, VtG, outp, attnp);
}

// Round 9
// 216.478 us; speedup vs baseline: 1.2124x; 1.0132x over previous
//
#include <hip/hip_runtime.h>
#include <hip/hip_bf16.h>

#define HID 1024
#define NHEADS 16
#define HDIM 64
#define SEQ 2048
#define NTOK 4096

typedef __attribute__((ext_vector_type(8))) short short8;
typedef __attribute__((ext_vector_type(4))) float f32x4;
typedef unsigned short ush;

__device__ __forceinline__ ush f2bf(float f) {
    unsigned int u = __float_as_uint(f);
    u = (u + 0x7fffu + ((u >> 16) & 1u)) >> 16;
    return (ush)u;
}
__device__ __forceinline__ void async_copy16(const void* g, void* l) {
    __builtin_amdgcn_global_load_lds(
        (const __attribute__((address_space(1))) void*)g,
        (__attribute__((address_space(3))) void*)l, 16, 0, 0);
}
#define SBAR()  __builtin_amdgcn_s_barrier()
#define SCHED() __builtin_amdgcn_sched_barrier(0)

// ---------------- Kernel 0: f32 -> bf16 convert (X and stacked W) ----------------
__global__ __launch_bounds__(256) void cvt_kernel(
    const float* __restrict__ X, const float* __restrict__ Wq,
    const float* __restrict__ Wk, const float* __restrict__ Wg,
    ush* __restrict__ Xbf, ush* __restrict__ Wbf)
{
    long i = (long)blockIdx.x * 256 + threadIdx.x;   // 917504 vec8 groups
    const float* src; ush* dst; long j;
    if (i < 524288)      { src = X;  dst = Xbf;           j = i; }
    else if (i < 655360) { src = Wq; dst = Wbf;           j = i - 524288; }
    else if (i < 786432) { src = Wk; dst = Wbf + 1048576; j = i - 655360; }
    else                 { src = Wg; dst = Wbf + 2097152; j = i - 786432; }
    float4 a = *reinterpret_cast<const float4*>(src + j * 8);
    float4 b = *reinterpret_cast<const float4*>(src + j * 8 + 4);
    short8 o;
    o[0] = (short)f2bf(a.x); o[1] = (short)f2bf(a.y);
    o[2] = (short)f2bf(a.z); o[3] = (short)f2bf(a.w);
    o[4] = (short)f2bf(b.x); o[5] = (short)f2bf(b.y);
    o[6] = (short)f2bf(b.z); o[7] = (short)f2bf(b.w);
    *reinterpret_cast<short8*>(dst + j * 8) = o;
}

// ---------------- Kernel 1: fused projection GEMM (N = 3072 = Q|K|gate) ----------------
// m97 structure: single-buffered 32KB LDS, stage -> vmcnt(0)+barrier -> MFMA
// -> barrier. 3 blocks/CU, 768 blocks fully resident (no tail).
// z==1 (K) also writes the per-head transposed copy VtG[bh][d][s] from regs.
__global__ __launch_bounds__(256, 3) void proj_kernel(
    const ush* __restrict__ Xbf, const ush* __restrict__ Wbf,
    const float* __restrict__ bgp,
    ush* __restrict__ Qbf, ush* __restrict__ Kbf,
    ush* __restrict__ VtG,
    float* __restrict__ gate)
{
    __shared__ __align__(16) ush As[128 * 64];
    __shared__ __align__(16) ush Bs[128 * 64];

    const int lin = blockIdx.y * 24 + blockIdx.x;   // 768 blocks, 768%8==0
    const int swz = (lin & 7) * 96 + (lin >> 3);
    const int n0 = (swz % 24) * 128;
    const int m0 = (swz / 24) * 128;
    const int tid = threadIdx.x, lane = tid & 63, wv = tid >> 6;
    const int wm = wv >> 1, wn = wv & 1;
    const int l16 = lane & 15, lq = lane >> 4;
    const int lrow = lane >> 3, lc = lane & 7;
    const int scU = lc ^ lrow;
    const int u0 = lq ^ (l16 & 7);

    f32x4 acc[4][4];
    #pragma unroll
    for (int i = 0; i < 4; i++)
        #pragma unroll
        for (int j = 0; j < 4; j++)
            #pragma unroll
            for (int r = 0; r < 4; r++) acc[i][j][r] = 0.0f;

    const ush* gA = Xbf + (long)m0 * HID;
    const ush* gB = Wbf + (long)n0 * HID;

    for (int k0 = 0; k0 < HID; k0 += 64) {
        #pragma unroll
        for (int c = 0; c < 4; ++c) {
            int chunk = wv * 4 + c;                  // wave-uniform
            int row = chunk * 8 + lrow;
            async_copy16(gA + (long)row * HID + k0 + scU * 8, &As[chunk * 512]);
            async_copy16(gB + (long)row * HID + k0 + scU * 8, &Bs[chunk * 512]);
        }
        asm volatile("s_waitcnt vmcnt(0)" ::: "memory");
        SCHED();
        SBAR(); SCHED();
        #pragma unroll
        for (int ks = 0; ks < 2; ++ks) {
            const int uo = (ks ? (u0 ^ 4) : u0) * 8;
            short8 a[4], b[4];
            #pragma unroll
            for (int mf = 0; mf < 4; mf++)
                a[mf] = *reinterpret_cast<const short8*>(&As[(wm * 64 + mf * 16 + l16) * 64 + uo]);
            #pragma unroll
            for (int nf = 0; nf < 4; nf++)
                b[nf] = *reinterpret_cast<const short8*>(&Bs[(wn * 64 + nf * 16 + l16) * 64 + uo]);
            #pragma unroll
            for (int mf = 0; mf < 4; mf++)
                #pragma unroll
                for (int nf = 0; nf < 4; nf++)
                    acc[mf][nf] = __builtin_amdgcn_mfma_f32_16x16x32_bf16(a[mf], b[nf], acc[mf][nf], 0, 0, 0);
        }
        SBAR(); SCHED();
    }

    const int z = n0 >> 10;   // 0=Q, 1=K, 2=gate
    #pragma unroll
    for (int mf = 0; mf < 4; mf++)
        #pragma unroll
        for (int nf = 0; nf < 4; nf++) {
            int row = m0 + wm * 64 + mf * 16 + lq * 4;
            int gcol = n0 + wn * 64 + nf * 16 + l16;
            int col = gcol & 1023;
            #pragma unroll
            for (int r = 0; r < 4; r++) {
                float v = acc[mf][nf][r];
                long idx = (long)(row + r) * HID + col;
                if (z == 0)      Qbf[idx] = f2bf(v * 0.18033688011112042f); // 0.125*log2e
                else if (z == 1) Kbf[idx] = f2bf(v);
                else {
                    float gv = 1.0f / (1.0f + __expf(-(v + bgp[col])));
                    __builtin_nontemporal_store(gv, &gate[idx]);
                }
            }
            if (z == 1) {
                // V-transpose write: 4 consecutive s for fixed (bh,d)
                int bb = row >> 11, s = row & 2047;
                int bh = bb * NHEADS + (col >> 6);
                int d  = col & 63;
                unsigned int w0, w1;
                asm volatile("v_cvt_pk_bf16_f32 %0, %1, %2" : "=v"(w0)
                             : "v"(acc[mf][nf][0]), "v"(acc[mf][nf][1]));
                asm volatile("v_cvt_pk_bf16_f32 %0, %1, %2" : "=v"(w1)
                             : "v"(acc[mf][nf][2]), "v"(acc[mf][nf][3]));
                *reinterpret_cast<uint2*>(&VtG[((long)bh * HDIM + d) * SEQ + s]) =
                    make_uint2(w0, w1);
            }
        }
}

// ---------------- Kernel 2: fused attention (swapped QK layout) ----------------
__global__ __launch_bounds__(256, 2) void attn_kernel(
    const ush* __restrict__ Qbf,
    const ush* __restrict__ Kbf,
    const ush* __restrict__ VtG,
    float* __restrict__ outp,      // [4096][1024], holds gate on entry
    float* __restrict__ attnp)     // [32][2048][2048]
{
    __shared__ __align__(16) ush Ks[128 * 64];
    // QsA: slots 0..2 = Q rotation (pass A & B); slot 3 (pass A only) aliases
    // the At region (pass B). At = QsA + 12288, [128][72].
    __shared__ __align__(16) ush QsA[3 * 4096 + 128 * 72];
    __shared__ __align__(16) ush Vt[2][64 * 64];

    ush (*At)[72] = reinterpret_cast<ush(*)[72]>(&QsA[12288]);

    const int lin = (blockIdx.z * 16 + blockIdx.y) * 16 + blockIdx.x; // 512, %8==0
    const int swzb = (lin & 7) * 64 + (lin >> 3);
    const int kblk = swzb & 15;
    const int h    = (swzb >> 4) & 15;
    const int b    = swzb >> 8;
    const int bh   = b * NHEADS + h;
    const int tb   = b * SEQ;
    const int colbase = h * HDIM;
    const int tid  = threadIdx.x;
    const int lane = tid & 63;
    const int wv   = tid >> 6;
    const int l16  = lane & 15, lq = lane >> 4;
    const int lrow = lane >> 3, lc = lane & 7;
    const int scU  = lc ^ lrow;
    const int u0   = lq ^ (l16 & 7);

    const ush* Krow = Kbf + (long)(tb + kblk * 128) * HID + colbase;

    auto stageK = [&]() {
        #pragma unroll
        for (int c = 0; c < 4; ++c) {
            int chunk = wv * 4 + c;
            int row = chunk * 8 + lrow;
            async_copy16(Krow + (long)row * HID + scU * 8, &Ks[chunk * 512]);
        }
    };
    auto stageQ = [&](int q0, int bu) {   // bu in 0..3
        #pragma unroll
        for (int c = 0; c < 2; ++c) {
            int chunk = wv * 2 + c;
            int row = chunk * 8 + lrow;
            async_copy16(Qbf + (long)(tb + q0 + row) * HID + colbase + scU * 8,
                         &QsA[bu * 4096 + chunk * 512]);
        }
    };
    auto stageV = [&](int q0, int bu) {
        #pragma unroll
        for (int c = 0; c < 2; ++c) {
            int chunk = wv * 2 + c;
            int row = chunk * 8 + lrow;           // row = d
            async_copy16(VtG + ((long)bh * HDIM + row) * SEQ + q0 + scU * 8,
                         &Vt[bu][chunk * 512]);
        }
    };

    // ======== pass A: lane-local exp2 sums per k (1 barrier/iter, 4-slot Q) ========
    stageK();
    stageQ(0, 0);
    stageQ(64, 1);

    float ps[2] = {0.0f, 0.0f};

    for (int i = 0; i < 32; ++i) {
        if (i >= 30) asm volatile("s_waitcnt vmcnt(0)" ::: "memory");
        else         asm volatile("s_waitcnt vmcnt(2)" ::: "memory");
        SCHED();
        SBAR(); SCHED();
        if (i < 30) stageQ((i + 2) * 64, (i + 2) & 3);

        f32x4 acc[4][2];
        #pragma unroll
        for (int x = 0; x < 4; x++)
            #pragma unroll
            for (int y = 0; y < 2; y++)
                #pragma unroll
                for (int r = 0; r < 4; r++) acc[x][y][r] = 0.0f;

        const ush* Qb = &QsA[(i & 3) * 4096];
        #pragma unroll
        for (int ks = 0; ks < 2; ks++) {
            const int uo = (ks ? (u0 ^ 4) : u0) * 8;
            short8 aq[4], bk[2];
            #pragma unroll
            for (int mf = 0; mf < 4; mf++)
                aq[mf] = *reinterpret_cast<const short8*>(&Qb[(mf * 16 + l16) * 64 + uo]);
            #pragma unroll
            for (int nf = 0; nf < 2; nf++)
                bk[nf] = *reinterpret_cast<const short8*>(&Ks[(wv * 32 + nf * 16 + l16) * 64 + uo]);
            #pragma unroll
            for (int mf = 0; mf < 4; mf++)
                #pragma unroll
                for (int nf = 0; nf < 2; nf++)
                    acc[mf][nf] = __builtin_amdgcn_mfma_f32_16x16x32_bf16(aq[mf], bk[nf], acc[mf][nf], 0, 0, 0);
        }

        #pragma unroll
        for (int nf = 0; nf < 2; nf++) {
            float s = 0.0f;
            #pragma unroll
            for (int mf = 0; mf < 4; mf++)
                #pragma unroll
                for (int r = 0; r < 4; r++)
                    s += exp2f(acc[mf][nf][r]);
            ps[nf] += s;
        }
    }

    // denom: sum over the 4 lq lanes holding the same k (l16)
    float inv_r[2];
    #pragma unroll
    for (int nf = 0; nf < 2; nf++) {
        float v = ps[nf];
        v += __shfl_xor(v, 16);
        v += __shfl_xor(v, 32);
        inv_r[nf] = 1.0f / v;
    }

    f32x4 octx[2][4];
    #pragma unroll
    for (int x = 0; x < 2; x++)
        #pragma unroll
        for (int y = 0; y < 4; y++)
            #pragma unroll
            for (int r = 0; r < 4; r++) octx[x][y][r] = 0.0f;

    // ======== pass B (3-slot Q rotation; slot 3 now serves as At) ========
    SBAR();   // ensure all waves done with pass A reads before At aliasing
    stageQ(0, 0); stageV(0, 0);
    stageQ(64, 1); stageV(64, 1);

    for (int i = 0; i < 32; ++i) {
        const int q0 = i << 6;
        if (i == 0)       asm volatile("s_waitcnt vmcnt(4)"  ::: "memory");
        else if (i == 1)  asm volatile("s_waitcnt vmcnt(12)" ::: "memory");
        else if (i == 31) asm volatile("s_waitcnt vmcnt(16)" ::: "memory");
        else              asm volatile("s_waitcnt vmcnt(20)" ::: "memory");
        SCHED();
        SBAR(); SCHED();
        if (i < 30) stageQ((i + 2) * 64, (i + 2) % 3);

        f32x4 acc[4][2];
        #pragma unroll
        for (int x = 0; x < 4; x++)
            #pragma unroll
            for (int y = 0; y < 2; y++)
                #pragma unroll
                for (int r = 0; r < 4; r++) acc[x][y][r] = 0.0f;

        const ush* Qb = &QsA[(i % 3) * 4096];
        #pragma unroll
        for (int ks = 0; ks < 2; ks++) {
            const int uo = (ks ? (u0 ^ 4) : u0) * 8;
            short8 aq[4], bk[2];
            #pragma unroll
            for (int mf = 0; mf < 4; mf++)
                aq[mf] = *reinterpret_cast<const short8*>(&Qb[(mf * 16 + l16) * 64 + uo]);
            #pragma unroll
            for (int nf = 0; nf < 2; nf++)
                bk[nf] = *reinterpret_cast<const short8*>(&Ks[(wv * 32 + nf * 16 + l16) * 64 + uo]);
            #pragma unroll
            for (int mf = 0; mf < 4; mf++)
                #pragma unroll
                for (int nf = 0; nf < 2; nf++)
                    acc[mf][nf] = __builtin_amdgcn_mfma_f32_16x16x32_bf16(aq[mf], bk[nf], acc[mf][nf], 0, 0, 0);
        }

        // softmax -> bf16 P into wave-private At rows
        #pragma unroll
        for (int nf = 0; nf < 2; nf++) {
            const int krl = wv * 32 + nf * 16 + l16;
            const float inv = inv_r[nf];
            #pragma unroll
            for (int mf = 0; mf < 4; mf++) {
                const int qc = mf * 16 + lq * 4;
                float p0 = exp2f(acc[mf][nf][0]) * inv;
                float p1 = exp2f(acc[mf][nf][1]) * inv;
                float p2 = exp2f(acc[mf][nf][2]) * inv;
                float p3 = exp2f(acc[mf][nf][3]) * inv;
                unsigned int w0, w1;
                asm volatile("v_cvt_pk_bf16_f32 %0, %1, %2" : "=v"(w0) : "v"(p0), "v"(p1));
                asm volatile("v_cvt_pk_bf16_f32 %0, %1, %2" : "=v"(w1) : "v"(p2), "v"(p3));
                *reinterpret_cast<uint2*>(&At[krl][qc]) = make_uint2(w0, w1);
            }
        }

        // drain At writes (wave-private), then pull store data into regs
        asm volatile("s_waitcnt lgkmcnt(0)" ::: "memory");
        SCHED();

        uint2 wreg[8];
        const int rlo = lane >> 4;            // 0..3
        const int qc  = (lane & 15) * 4;      // 0..60
        #pragma unroll
        for (int j = 0; j < 8; ++j)
            wreg[j] = *reinterpret_cast<const uint2*>(&At[wv * 32 + j * 4 + rlo][qc]);

        // PV: ctx[k][d] += P[k][q] * Vt[d][q]
        #pragma unroll
        for (int ks = 0; ks < 2; ks++) {
            const int uo = (ks ? (u0 ^ 4) : u0) * 8;
            short8 a[2], bv[4];
            #pragma unroll
            for (int mf = 0; mf < 2; mf++)
                a[mf] = *reinterpret_cast<const short8*>(&At[wv * 32 + mf * 16 + l16][ks * 32 + lq * 8]);
            #pragma unroll
            for (int nf = 0; nf < 4; nf++)
                bv[nf] = *reinterpret_cast<const short8*>(&Vt[i & 1][(nf * 16 + l16) * 64 + uo]);
            #pragma unroll
            for (int mf = 0; mf < 2; mf++)
                #pragma unroll
                for (int nf = 0; nf < 4; nf++)
                    octx[mf][nf] = __builtin_amdgcn_mfma_f32_16x16x32_bf16(a[mf], bv[nf], octx[mf][nf], 0, 0, 0);
        }

        SBAR(); SCHED();
        if (i < 30) stageV((i + 2) * 64, i & 1);

        // attn stores LAST: 4 rows x 256B contiguous per instr, nontemporal
        #pragma unroll
        for (int j = 0; j < 8; ++j) {
            const int rl = wv * 32 + j * 4 + rlo;
            f32x4 st;
            st[0] = __uint_as_float(wreg[j].x << 16);
            st[1] = __uint_as_float(wreg[j].x & 0xffff0000u);
            st[2] = __uint_as_float(wreg[j].y << 16);
            st[3] = __uint_as_float(wreg[j].y & 0xffff0000u);
            __builtin_nontemporal_store(st,
                reinterpret_cast<f32x4*>(attnp + ((long)bh * SEQ + kblk * 128 + rl) * SEQ + q0 + qc));
        }
    }

    // epilogue: out = gate * ctx (nontemporal in/out)
    #pragma unroll
    for (int mf = 0; mf < 2; mf++)
        #pragma unroll
        for (int nf = 0; nf < 4; nf++) {
            int row = tb + kblk * 128 + wv * 32 + mf * 16 + lq * 4;
            int col = colbase + nf * 16 + l16;
            #pragma unroll
            for (int r = 0; r < 4; r++) {
                long idx = (long)(row + r) * HID + col;
                float g = __builtin_nontemporal_load(&outp[idx]);
                __builtin_nontemporal_store(g * octx[mf][nf][r], &outp[idx]);
            }
        }
}

extern "C" void kernel_launch(void* const* d_in, const int* in_sizes, int n_in,
                              void* d_out, int out_size, void* d_ws, size_t ws_size,
                              hipStream_t stream)
{
    const float* X  = (const float*)d_in[0];
    const float* Wq = (const float*)d_in[1];
    const float* Wk = (const float*)d_in[2];
    const float* Wg = (const float*)d_in[3];
    const float* bg = (const float*)d_in[4];

    float* outp  = (float*)d_out;
    float* attnp = outp + (long)NTOK * HID;

    ush* Qbf = (ush*)d_ws;
    ush* Kbf = Qbf + (long)NTOK * HID;
    ush* VtG = Kbf + (long)NTOK * HID;

    ush* Xbf = (ush*)(outp + 134742016L);
    ush* Wbf = Xbf + (long)NTOK * HID;

    cvt_kernel<<<3584, 256, 0, stream>>>(X, Wq, Wk, Wg, Xbf, Wbf);
    proj_kernel<<<dim3(24, 32), 256, 0, stream>>>(Xbf, Wbf, bg, Qbf, Kbf, VtG, outp);
    attn_kernel<<<dim3(16, 16, 2), 256, 0, stream>>>(Qbf, Kbf, VtG, outp, attnp);
}

// Round 10
// 214.210 us; speedup vs baseline: 1.2252x; 1.0106x over previous
//
#include <hip/hip_runtime.h>
#include <hip/hip_bf16.h>

#define HID 1024
#define NHEADS 16
#define HDIM 64
#define SEQ 2048
#define NTOK 4096

typedef __attribute__((ext_vector_type(8))) short short8;
typedef __attribute__((ext_vector_type(4))) float f32x4;
typedef unsigned short ush;

__device__ __forceinline__ ush f2bf(float f) {
    unsigned int u = __float_as_uint(f);
    u = (u + 0x7fffu + ((u >> 16) & 1u)) >> 16;
    return (ush)u;
}
__device__ __forceinline__ void async_copy16(const void* g, void* l) {
    __builtin_amdgcn_global_load_lds(
        (const __attribute__((address_space(1))) void*)g,
        (__attribute__((address_space(3))) void*)l, 16, 0, 0);
}
#define SBAR()  __builtin_amdgcn_s_barrier()
#define SCHED() __builtin_amdgcn_sched_barrier(0)

// ---------------- Kernel 0: f32 -> bf16 convert (X and stacked W) ----------------
__global__ __launch_bounds__(256) void cvt_kernel(
    const float* __restrict__ X, const float* __restrict__ Wq,
    const float* __restrict__ Wk, const float* __restrict__ Wg,
    ush* __restrict__ Xbf, ush* __restrict__ Wbf)
{
    long i = (long)blockIdx.x * 256 + threadIdx.x;   // 917504 vec8 groups
    const float* src; ush* dst; long j;
    if (i < 524288)      { src = X;  dst = Xbf;           j = i; }
    else if (i < 655360) { src = Wq; dst = Wbf;           j = i - 524288; }
    else if (i < 786432) { src = Wk; dst = Wbf + 1048576; j = i - 655360; }
    else                 { src = Wg; dst = Wbf + 2097152; j = i - 786432; }
    float4 a = *reinterpret_cast<const float4*>(src + j * 8);
    float4 b = *reinterpret_cast<const float4*>(src + j * 8 + 4);
    short8 o;
    o[0] = (short)f2bf(a.x); o[1] = (short)f2bf(a.y);
    o[2] = (short)f2bf(a.z); o[3] = (short)f2bf(a.w);
    o[4] = (short)f2bf(b.x); o[5] = (short)f2bf(b.y);
    o[6] = (short)f2bf(b.z); o[7] = (short)f2bf(b.w);
    *reinterpret_cast<short8*>(dst + j * 8) = o;
}

// ---------------- Kernel 1: fused projection GEMM (N = 3072 = Q|K|gate) ----------------
// m97 structure: single-buffered 32KB LDS, stage -> vmcnt(0)+barrier -> MFMA
// -> barrier. 3 blocks/CU, 768 blocks fully resident.
__global__ __launch_bounds__(256, 3) void proj_kernel(
    const ush* __restrict__ Xbf, const ush* __restrict__ Wbf,
    const float* __restrict__ bgp,
    ush* __restrict__ Qbf, ush* __restrict__ Kbf,
    ush* __restrict__ VtG,
    float* __restrict__ gate)
{
    __shared__ __align__(16) ush As[128 * 64];
    __shared__ __align__(16) ush Bs[128 * 64];

    const int lin = blockIdx.y * 24 + blockIdx.x;   // 768 blocks, 768%8==0
    const int swz = (lin & 7) * 96 + (lin >> 3);
    const int n0 = (swz % 24) * 128;
    const int m0 = (swz / 24) * 128;
    const int tid = threadIdx.x, lane = tid & 63, wv = tid >> 6;
    const int wm = wv >> 1, wn = wv & 1;
    const int l16 = lane & 15, lq = lane >> 4;
    const int lrow = lane >> 3, lc = lane & 7;
    const int scU = lc ^ lrow;
    const int u0 = lq ^ (l16 & 7);

    f32x4 acc[4][4];
    #pragma unroll
    for (int i = 0; i < 4; i++)
        #pragma unroll
        for (int j = 0; j < 4; j++)
            #pragma unroll
            for (int r = 0; r < 4; r++) acc[i][j][r] = 0.0f;

    const ush* gA = Xbf + (long)m0 * HID;
    const ush* gB = Wbf + (long)n0 * HID;

    for (int k0 = 0; k0 < HID; k0 += 64) {
        #pragma unroll
        for (int c = 0; c < 4; ++c) {
            int chunk = wv * 4 + c;                  // wave-uniform
            int row = chunk * 8 + lrow;
            async_copy16(gA + (long)row * HID + k0 + scU * 8, &As[chunk * 512]);
            async_copy16(gB + (long)row * HID + k0 + scU * 8, &Bs[chunk * 512]);
        }
        asm volatile("s_waitcnt vmcnt(0)" ::: "memory");
        SCHED();
        SBAR(); SCHED();
        #pragma unroll
        for (int ks = 0; ks < 2; ++ks) {
            const int uo = (ks ? (u0 ^ 4) : u0) * 8;
            short8 a[4], b[4];
            #pragma unroll
            for (int mf = 0; mf < 4; mf++)
                a[mf] = *reinterpret_cast<const short8*>(&As[(wm * 64 + mf * 16 + l16) * 64 + uo]);
            #pragma unroll
            for (int nf = 0; nf < 4; nf++)
                b[nf] = *reinterpret_cast<const short8*>(&Bs[(wn * 64 + nf * 16 + l16) * 64 + uo]);
            #pragma unroll
            for (int mf = 0; mf < 4; mf++)
                #pragma unroll
                for (int nf = 0; nf < 4; nf++)
                    acc[mf][nf] = __builtin_amdgcn_mfma_f32_16x16x32_bf16(a[mf], b[nf], acc[mf][nf], 0, 0, 0);
        }
        SBAR(); SCHED();
    }

    const int z = n0 >> 10;   // 0=Q, 1=K, 2=gate
    #pragma unroll
    for (int mf = 0; mf < 4; mf++)
        #pragma unroll
        for (int nf = 0; nf < 4; nf++) {
            int row = m0 + wm * 64 + mf * 16 + lq * 4;
            int gcol = n0 + wn * 64 + nf * 16 + l16;
            int col = gcol & 1023;
            #pragma unroll
            for (int r = 0; r < 4; r++) {
                float v = acc[mf][nf][r];
                long idx = (long)(row + r) * HID + col;
                if (z == 0)      Qbf[idx] = f2bf(v * 0.18033688011112042f); // 0.125*log2e
                else if (z == 1) Kbf[idx] = f2bf(v);
                else {
                    float gv = 1.0f / (1.0f + __expf(-(v + bgp[col])));
                    __builtin_nontemporal_store(gv, &gate[idx]);
                }
            }
            if (z == 1) {
                // V-transpose write: 4 consecutive s for fixed (bh,d)
                int bb = row >> 11, s = row & 2047;
                int bh = bb * NHEADS + (col >> 6);
                int d  = col & 63;
                unsigned int w0, w1;
                asm volatile("v_cvt_pk_bf16_f32 %0, %1, %2" : "=v"(w0)
                             : "v"(acc[mf][nf][0]), "v"(acc[mf][nf][1]));
                asm volatile("v_cvt_pk_bf16_f32 %0, %1, %2" : "=v"(w1)
                             : "v"(acc[mf][nf][2]), "v"(acc[mf][nf][3]));
                *reinterpret_cast<uint2*>(&VtG[((long)bh * HDIM + d) * SEQ + s]) =
                    make_uint2(w0, w1);
            }
        }
}

// ---------------- Kernel 2: fused attention (swapped QK, K in registers) ----------------
// LDS 50KB -> 3 blocks/CU (12 waves/CU). K staged once through the At region
// into 16 VGPR of loop-invariant MFMA B-fragments; V single-buffered.
__global__ __launch_bounds__(256, 3) void attn_kernel(
    const ush* __restrict__ Qbf,
    const ush* __restrict__ Kbf,
    const ush* __restrict__ VtG,
    float* __restrict__ outp,      // [4096][1024], holds gate on entry
    float* __restrict__ attnp)     // [32][2048][2048]
{
    __shared__ __align__(16) ush QsA[3 * 4096];     // 24 KB: Q 3-slot rotation
    __shared__ __align__(16) ush AtA[128 * 72];     // 18.4 KB: P tile (pass B); K staging at start
    __shared__ __align__(16) ush VtA[64 * 64];      // 8 KB: V tile (single)

    ush (*At)[72] = reinterpret_cast<ush(*)[72]>(&AtA[0]);

    const int lin = (blockIdx.z * 16 + blockIdx.y) * 16 + blockIdx.x; // 512, %8==0
    const int swzb = (lin & 7) * 64 + (lin >> 3);
    const int kblk = swzb & 15;
    const int h    = (swzb >> 4) & 15;
    const int b    = swzb >> 8;
    const int bh   = b * NHEADS + h;
    const int tb   = b * SEQ;
    const int colbase = h * HDIM;
    const int tid  = threadIdx.x;
    const int lane = tid & 63;
    const int wv   = tid >> 6;
    const int l16  = lane & 15, lq = lane >> 4;
    const int lrow = lane >> 3, lc = lane & 7;
    const int scU  = lc ^ lrow;
    const int u0   = lq ^ (l16 & 7);

    const ush* Krow = Kbf + (long)(tb + kblk * 128) * HID + colbase;

    auto stageQ = [&](int q0, int bu) {   // bu in 0..2
        #pragma unroll
        for (int c = 0; c < 2; ++c) {
            int chunk = wv * 2 + c;
            int row = chunk * 8 + lrow;
            async_copy16(Qbf + (long)(tb + q0 + row) * HID + colbase + scU * 8,
                         &QsA[bu * 4096 + chunk * 512]);
        }
    };
    auto stageV = [&](int q0) {
        #pragma unroll
        for (int c = 0; c < 2; ++c) {
            int chunk = wv * 2 + c;
            int row = chunk * 8 + lrow;           // row = d
            async_copy16(VtG + ((long)bh * HDIM + row) * SEQ + q0 + scU * 8,
                         &VtA[chunk * 512]);
        }
    };

    // ---- K -> registers via At-region staging (done once) ----
    short8 bk[2][2];   // [ks][nf] loop-invariant MFMA B fragments, 16 VGPR
    {
        #pragma unroll
        for (int c = 0; c < 4; ++c) {
            int chunk = wv * 4 + c;
            int row = chunk * 8 + lrow;
            async_copy16(Krow + (long)row * HID + scU * 8, &AtA[chunk * 512]);
        }
        asm volatile("s_waitcnt vmcnt(0)" ::: "memory");
        SCHED();
        SBAR(); SCHED();
        #pragma unroll
        for (int ks = 0; ks < 2; ++ks) {
            const int uo = (ks ? (u0 ^ 4) : u0) * 8;
            #pragma unroll
            for (int nf = 0; nf < 2; ++nf)
                bk[ks][nf] = *reinterpret_cast<const short8*>(
                    &AtA[(wv * 32 + nf * 16 + l16) * 64 + uo]);
        }
        SBAR(); SCHED();   // all waves done reading K before At reuse (pass B)
    }

    // ======== pass A: lane-local exp2 sums per k (1 barrier/iter, 3-slot Q) ========
    stageQ(0, 0);
    stageQ(64, 1);

    float ps[2] = {0.0f, 0.0f};

    for (int i = 0; i < 32; ++i) {
        if (i >= 30) asm volatile("s_waitcnt vmcnt(0)" ::: "memory");
        else         asm volatile("s_waitcnt vmcnt(2)" ::: "memory");
        SCHED();
        SBAR(); SCHED();
        if (i < 30) stageQ((i + 2) * 64, (i + 2) % 3);

        f32x4 acc[4][2];
        #pragma unroll
        for (int x = 0; x < 4; x++)
            #pragma unroll
            for (int y = 0; y < 2; y++)
                #pragma unroll
                for (int r = 0; r < 4; r++) acc[x][y][r] = 0.0f;

        const ush* Qb = &QsA[(i % 3) * 4096];
        __builtin_amdgcn_s_setprio(1);
        #pragma unroll
        for (int ks = 0; ks < 2; ks++) {
            const int uo = (ks ? (u0 ^ 4) : u0) * 8;
            short8 aq[4];
            #pragma unroll
            for (int mf = 0; mf < 4; mf++)
                aq[mf] = *reinterpret_cast<const short8*>(&Qb[(mf * 16 + l16) * 64 + uo]);
            #pragma unroll
            for (int mf = 0; mf < 4; mf++)
                #pragma unroll
                for (int nf = 0; nf < 2; nf++)
                    acc[mf][nf] = __builtin_amdgcn_mfma_f32_16x16x32_bf16(aq[mf], bk[ks][nf], acc[mf][nf], 0, 0, 0);
        }
        __builtin_amdgcn_s_setprio(0);

        #pragma unroll
        for (int nf = 0; nf < 2; nf++) {
            float s = 0.0f;
            #pragma unroll
            for (int mf = 0; mf < 4; mf++)
                #pragma unroll
                for (int r = 0; r < 4; r++)
                    s += exp2f(acc[mf][nf][r]);
            ps[nf] += s;
        }
    }

    // denom: sum over the 4 lq lanes holding the same k (l16)
    float inv_r[2];
    #pragma unroll
    for (int nf = 0; nf < 2; nf++) {
        float v = ps[nf];
        v += __shfl_xor(v, 16);
        v += __shfl_xor(v, 32);
        inv_r[nf] = 1.0f / v;
    }

    f32x4 octx[2][4];
    #pragma unroll
    for (int x = 0; x < 2; x++)
        #pragma unroll
        for (int y = 0; y < 4; y++)
            #pragma unroll
            for (int r = 0; r < 4; r++) octx[x][y][r] = 0.0f;

    // ======== pass B ========
    SBAR();   // all waves done with pass A before At/V reuse
    stageQ(0, 0);
    stageV(0);
    stageQ(64, 1);

    for (int i = 0; i < 32; ++i) {
        const int q0 = i << 6;
        if (i == 0) asm volatile("s_waitcnt vmcnt(2)" ::: "memory");
        else        asm volatile("s_waitcnt vmcnt(8)" ::: "memory");
        SCHED();
        SBAR(); SCHED();
        if (i < 30) stageQ((i + 2) * 64, (i + 2) % 3);

        f32x4 acc[4][2];
        #pragma unroll
        for (int x = 0; x < 4; x++)
            #pragma unroll
            for (int y = 0; y < 2; y++)
                #pragma unroll
                for (int r = 0; r < 4; r++) acc[x][y][r] = 0.0f;

        const ush* Qb = &QsA[(i % 3) * 4096];
        __builtin_amdgcn_s_setprio(1);
        #pragma unroll
        for (int ks = 0; ks < 2; ks++) {
            const int uo = (ks ? (u0 ^ 4) : u0) * 8;
            short8 aq[4];
            #pragma unroll
            for (int mf = 0; mf < 4; mf++)
                aq[mf] = *reinterpret_cast<const short8*>(&Qb[(mf * 16 + l16) * 64 + uo]);
            #pragma unroll
            for (int mf = 0; mf < 4; mf++)
                #pragma unroll
                for (int nf = 0; nf < 2; nf++)
                    acc[mf][nf] = __builtin_amdgcn_mfma_f32_16x16x32_bf16(aq[mf], bk[ks][nf], acc[mf][nf], 0, 0, 0);
        }
        __builtin_amdgcn_s_setprio(0);

        // softmax -> bf16 P into wave-private At rows
        #pragma unroll
        for (int nf = 0; nf < 2; nf++) {
            const int krl = wv * 32 + nf * 16 + l16;
            const float inv = inv_r[nf];
            #pragma unroll
            for (int mf = 0; mf < 4; mf++) {
                const int qc = mf * 16 + lq * 4;
                float p0 = exp2f(acc[mf][nf][0]) * inv;
                float p1 = exp2f(acc[mf][nf][1]) * inv;
                float p2 = exp2f(acc[mf][nf][2]) * inv;
                float p3 = exp2f(acc[mf][nf][3]) * inv;
                unsigned int w0, w1;
                asm volatile("v_cvt_pk_bf16_f32 %0, %1, %2" : "=v"(w0) : "v"(p0), "v"(p1));
                asm volatile("v_cvt_pk_bf16_f32 %0, %1, %2" : "=v"(w1) : "v"(p2), "v"(p3));
                *reinterpret_cast<uint2*>(&At[krl][qc]) = make_uint2(w0, w1);
            }
        }

        // drain At writes (wave-private), then pull store data into regs
        asm volatile("s_waitcnt lgkmcnt(0)" ::: "memory");
        SCHED();

        uint2 wreg[8];
        const int rlo = lane >> 4;            // 0..3
        const int qc  = (lane & 15) * 4;      // 0..60
        #pragma unroll
        for (int j = 0; j < 8; ++j)
            wreg[j] = *reinterpret_cast<const uint2*>(&At[wv * 32 + j * 4 + rlo][qc]);

        // PV: ctx[k][d] += P[k][q] * Vt[d][q]
        __builtin_amdgcn_s_setprio(1);
        #pragma unroll
        for (int ks = 0; ks < 2; ks++) {
            const int uo = (ks ? (u0 ^ 4) : u0) * 8;
            short8 a[2], bv[4];
            #pragma unroll
            for (int mf = 0; mf < 2; mf++)
                a[mf] = *reinterpret_cast<const short8*>(&At[wv * 32 + mf * 16 + l16][ks * 32 + lq * 8]);
            #pragma unroll
            for (int nf = 0; nf < 4; nf++)
                bv[nf] = *reinterpret_cast<const short8*>(&VtA[(nf * 16 + l16) * 64 + uo]);
            #pragma unroll
            for (int mf = 0; mf < 2; mf++)
                #pragma unroll
                for (int nf = 0; nf < 4; nf++)
                    octx[mf][nf] = __builtin_amdgcn_mfma_f32_16x16x32_bf16(a[mf], bv[nf], octx[mf][nf], 0, 0, 0);
        }
        __builtin_amdgcn_s_setprio(0);

        SBAR(); SCHED();                       // all waves done reading VtA
        if (i < 31) stageV((i + 1) * 64);      // refill single V buffer

        // attn stores LAST: 4 rows x 256B contiguous per instr, nontemporal
        #pragma unroll
        for (int j = 0; j < 8; ++j) {
            const int rl = wv * 32 + j * 4 + rlo;
            f32x4 st;
            st[0] = __uint_as_float(wreg[j].x << 16);
            st[1] = __uint_as_float(wreg[j].x & 0xffff0000u);
            st[2] = __uint_as_float(wreg[j].y << 16);
            st[3] = __uint_as_float(wreg[j].y & 0xffff0000u);
            __builtin_nontemporal_store(st,
                reinterpret_cast<f32x4*>(attnp + ((long)bh * SEQ + kblk * 128 + rl) * SEQ + q0 + qc));
        }
    }

    // epilogue: out = gate * ctx (nontemporal in/out)
    #pragma unroll
    for (int mf = 0; mf < 2; mf++)
        #pragma unroll
        for (int nf = 0; nf < 4; nf++) {
            int row = tb + kblk * 128 + wv * 32 + mf * 16 + lq * 4;
            int col = colbase + nf * 16 + l16;
            #pragma unroll
            for (int r = 0; r < 4; r++) {
                long idx = (long)(row + r) * HID + col;
                float g = __builtin_nontemporal_load(&outp[idx]);
                __builtin_nontemporal_store(g * octx[mf][nf][r], &outp[idx]);
            }
        }
}

extern "C" void kernel_launch(void* const* d_in, const int* in_sizes, int n_in,
                              void* d_out, int out_size, void* d_ws, size_t ws_size,
                              hipStream_t stream)
{
    const float* X  = (const float*)d_in[0];
    const float* Wq = (const float*)d_in[1];
    const float* Wk = (const float*)d_in[2];
    const float* Wg = (const float*)d_in[3];
    const float* bg = (const float*)d_in[4];

    float* outp  = (float*)d_out;
    float* attnp = outp + (long)NTOK * HID;

    ush* Qbf = (ush*)d_ws;
    ush* Kbf = Qbf + (long)NTOK * HID;
    ush* VtG = Kbf + (long)NTOK * HID;

    ush* Xbf = (ush*)(outp + 134742016L);
    ush* Wbf = Xbf + (long)NTOK * HID;

    cvt_kernel<<<3584, 256, 0, stream>>>(X, Wq, Wk, Wg, Xbf, Wbf);
    proj_kernel<<<dim3(24, 32), 256, 0, stream>>>(Xbf, Wbf, bg, Qbf, Kbf, VtG, outp);
    attn_kernel<<<dim3(16, 16, 2), 256, 0, stream>>>(Qbf, Kbf, VtG, outp, attnp);
}

// Round 11
// 206.155 us; speedup vs baseline: 1.2731x; 1.0391x over previous
//
#include <hip/hip_runtime.h>
#include <hip/hip_bf16.h>

#define HID 1024
#define NHEADS 16
#define HDIM 64
#define SEQ 2048
#define NTOK 4096

typedef __attribute__((ext_vector_type(8))) short short8;
typedef __attribute__((ext_vector_type(4))) float f32x4;
typedef unsigned short ush;

__device__ __forceinline__ ush f2bf(float f) {
    unsigned int u = __float_as_uint(f);
    u = (u + 0x7fffu + ((u >> 16) & 1u)) >> 16;
    return (ush)u;
}
__device__ __forceinline__ void async_copy16(const void* g, void* l) {
    __builtin_amdgcn_global_load_lds(
        (const __attribute__((address_space(1))) void*)g,
        (__attribute__((address_space(3))) void*)l, 16, 0, 0);
}
#define SBAR()  __builtin_amdgcn_s_barrier()
#define SCHED() __builtin_amdgcn_sched_barrier(0)

// ---------------- Kernel 0: f32 -> bf16 convert (X and stacked W) ----------------
__global__ __launch_bounds__(256) void cvt_kernel(
    const float* __restrict__ X, const float* __restrict__ Wq,
    const float* __restrict__ Wk, const float* __restrict__ Wg,
    ush* __restrict__ Xbf, ush* __restrict__ Wbf)
{
    long i = (long)blockIdx.x * 256 + threadIdx.x;   // 917504 vec8 groups
    const float* src; ush* dst; long j;
    if (i < 524288)      { src = X;  dst = Xbf;           j = i; }
    else if (i < 655360) { src = Wq; dst = Wbf;           j = i - 524288; }
    else if (i < 786432) { src = Wk; dst = Wbf + 1048576; j = i - 655360; }
    else                 { src = Wg; dst = Wbf + 2097152; j = i - 786432; }
    float4 a = *reinterpret_cast<const float4*>(src + j * 8);
    float4 b = *reinterpret_cast<const float4*>(src + j * 8 + 4);
    short8 o;
    o[0] = (short)f2bf(a.x); o[1] = (short)f2bf(a.y);
    o[2] = (short)f2bf(a.z); o[3] = (short)f2bf(a.w);
    o[4] = (short)f2bf(b.x); o[5] = (short)f2bf(b.y);
    o[6] = (short)f2bf(b.z); o[7] = (short)f2bf(b.w);
    *reinterpret_cast<short8*>(dst + j * 8) = o;
}

// ---------------- Kernel 1: fused projection GEMM (N = 3072 = Q|K|gate) ----------------
__global__ __launch_bounds__(256, 3) void proj_kernel(
    const ush* __restrict__ Xbf, const ush* __restrict__ Wbf,
    const float* __restrict__ bgp,
    ush* __restrict__ Qbf, ush* __restrict__ Kbf,
    ush* __restrict__ VtG,
    float* __restrict__ gate)
{
    __shared__ __align__(16) ush As[128 * 64];
    __shared__ __align__(16) ush Bs[128 * 64];

    const int lin = blockIdx.y * 24 + blockIdx.x;   // 768 blocks, 768%8==0
    const int swz = (lin & 7) * 96 + (lin >> 3);
    const int n0 = (swz % 24) * 128;
    const int m0 = (swz / 24) * 128;
    const int tid = threadIdx.x, lane = tid & 63, wv = tid >> 6;
    const int wm = wv >> 1, wn = wv & 1;
    const int l16 = lane & 15, lq = lane >> 4;
    const int lrow = lane >> 3, lc = lane & 7;
    const int scU = lc ^ lrow;
    const int u0 = lq ^ (l16 & 7);

    f32x4 acc[4][4];
    #pragma unroll
    for (int i = 0; i < 4; i++)
        #pragma unroll
        for (int j = 0; j < 4; j++)
            #pragma unroll
            for (int r = 0; r < 4; r++) acc[i][j][r] = 0.0f;

    const ush* gA = Xbf + (long)m0 * HID;
    const ush* gB = Wbf + (long)n0 * HID;

    for (int k0 = 0; k0 < HID; k0 += 64) {
        #pragma unroll
        for (int c = 0; c < 4; ++c) {
            int chunk = wv * 4 + c;                  // wave-uniform
            int row = chunk * 8 + lrow;
            async_copy16(gA + (long)row * HID + k0 + scU * 8, &As[chunk * 512]);
            async_copy16(gB + (long)row * HID + k0 + scU * 8, &Bs[chunk * 512]);
        }
        asm volatile("s_waitcnt vmcnt(0)" ::: "memory");
        SCHED();
        SBAR(); SCHED();
        #pragma unroll
        for (int ks = 0; ks < 2; ++ks) {
            const int uo = (ks ? (u0 ^ 4) : u0) * 8;
            short8 a[4], b[4];
            #pragma unroll
            for (int mf = 0; mf < 4; mf++)
                a[mf] = *reinterpret_cast<const short8*>(&As[(wm * 64 + mf * 16 + l16) * 64 + uo]);
            #pragma unroll
            for (int nf = 0; nf < 4; nf++)
                b[nf] = *reinterpret_cast<const short8*>(&Bs[(wn * 64 + nf * 16 + l16) * 64 + uo]);
            #pragma unroll
            for (int mf = 0; mf < 4; mf++)
                #pragma unroll
                for (int nf = 0; nf < 4; nf++)
                    acc[mf][nf] = __builtin_amdgcn_mfma_f32_16x16x32_bf16(a[mf], b[nf], acc[mf][nf], 0, 0, 0);
        }
        SBAR(); SCHED();
    }

    const int z = n0 >> 10;   // 0=Q, 1=K, 2=gate
    #pragma unroll
    for (int mf = 0; mf < 4; mf++)
        #pragma unroll
        for (int nf = 0; nf < 4; nf++) {
            int row = m0 + wm * 64 + mf * 16 + lq * 4;
            int gcol = n0 + wn * 64 + nf * 16 + l16;
            int col = gcol & 1023;
            #pragma unroll
            for (int r = 0; r < 4; r++) {
                float v = acc[mf][nf][r];
                long idx = (long)(row + r) * HID + col;
                if (z == 0)      Qbf[idx] = f2bf(v * 0.18033688011112042f); // 0.125*log2e
                else if (z == 1) Kbf[idx] = f2bf(v);
                else {
                    float gv = 1.0f / (1.0f + __expf(-(v + bgp[col])));
                    __builtin_nontemporal_store(gv, &gate[idx]);
                }
            }
            if (z == 1) {
                int bb = row >> 11, s = row & 2047;
                int bh = bb * NHEADS + (col >> 6);
                int d  = col & 63;
                unsigned int w0, w1;
                asm volatile("v_cvt_pk_bf16_f32 %0, %1, %2" : "=v"(w0)
                             : "v"(acc[mf][nf][0]), "v"(acc[mf][nf][1]));
                asm volatile("v_cvt_pk_bf16_f32 %0, %1, %2" : "=v"(w1)
                             : "v"(acc[mf][nf][2]), "v"(acc[mf][nf][3]));
                *reinterpret_cast<uint2*>(&VtG[((long)bh * HDIM + d) * SEQ + s]) =
                    make_uint2(w0, w1);
            }
        }
}

// ---------------- Kernel 2: attention, 3-sweep kblk-pair pipeline ----------------
// Block owns 64 rows of kblk a AND 64 rows of kblk b (same head).
// sweep1: denom(a). sweep2: write+PV(a) fused with denom(b). sweep3: write+PV(b).
// HBM write stream active during sweeps 2+3 (~80% of lifetime).
__global__ __launch_bounds__(256, 2) void attn_kernel(
    const ush* __restrict__ Qbf,
    const ush* __restrict__ Kbf,
    const ush* __restrict__ VtG,
    float* __restrict__ outp,      // [4096][1024], holds gate on entry
    float* __restrict__ attnp)     // [32][2048][2048]
{
    __shared__ __align__(16) ush QsA[3 * 4096];   // 24 KB  Q 3-slot rotation
    __shared__ __align__(16) ush AtA[64 * 72];    // 9.2 KB K staging scratch / P tile
    __shared__ __align__(16) ush VtA[64 * 64];    // 8 KB   V tile (single)

    ush (*At)[72] = reinterpret_cast<ush(*)[72]>(&AtA[0]);

    const int lin  = blockIdx.x;                    // 512 blocks, %8==0
    const int swzb = (lin & 7) * 64 + (lin >> 3);
    const int rh   = swzb & 1;
    const int pair = (swzb >> 1) & 7;
    const int h    = (swzb >> 4) & 15;
    const int b    = swzb >> 8;
    const int bh   = b * NHEADS + h;
    const int tb   = b * SEQ;
    const int colbase = h * HDIM;
    const int rowbase_a = pair * 256 + rh * 64;     // kb_a*128 + rh*64
    const int rowbase_b = rowbase_a + 128;          // kb_b*128 + rh*64

    const int tid  = threadIdx.x;
    const int lane = tid & 63;
    const int wv   = tid >> 6;
    const int l16  = lane & 15, lq = lane >> 4;
    const int u0   = lq ^ (l16 & 7);
    const int rlo  = lane >> 4;            // 0..3
    const int qc2  = (lane & 15) * 4;      // 0..60

    // stage a 64x64 bf16 tile with both-sides XOR swizzle (2 copies/thread)
    auto stageT = [&](const ush* src, long stride, ush* dst) {
        #pragma unroll
        for (int c = 0; c < 2; ++c) {
            int p = c * 256 + tid;
            int row = p >> 3, lc2 = p & 7;
            int scU2 = lc2 ^ (row & 7);
            async_copy16(src + (long)row * stride + scU2 * 8, dst + c * 2048 + wv * 512);
        }
    };
    const ush* Qsrc = Qbf + (long)tb * HID + colbase;
    const ush* Vsrc = VtG + (long)bh * HDIM * SEQ;

    // ---- K(a), K(b) -> registers via AtA staging ----
    short8 bk_a[2], bk_b[2];
    {
        stageT(Kbf + (long)(tb + rowbase_a) * HID + colbase, HID, AtA);
        asm volatile("s_waitcnt vmcnt(0)" ::: "memory"); SCHED();
        SBAR(); SCHED();
        #pragma unroll
        for (int ks = 0; ks < 2; ++ks) {
            const int uo = (ks ? (u0 ^ 4) : u0) * 8;
            bk_a[ks] = *reinterpret_cast<const short8*>(&AtA[(wv * 16 + l16) * 64 + uo]);
        }
        SBAR(); SCHED();
        stageT(Kbf + (long)(tb + rowbase_b) * HID + colbase, HID, AtA);
        asm volatile("s_waitcnt vmcnt(0)" ::: "memory"); SCHED();
        SBAR(); SCHED();
        #pragma unroll
        for (int ks = 0; ks < 2; ++ks) {
            const int uo = (ks ? (u0 ^ 4) : u0) * 8;
            bk_b[ks] = *reinterpret_cast<const short8*>(&AtA[(wv * 16 + l16) * 64 + uo]);
        }
        SBAR(); SCHED();
    }

    // ======== sweep 1: denom(a) ========
    stageT(Qsrc, HID, &QsA[0]);
    stageT(Qsrc + (long)64 * HID, HID, &QsA[4096]);

    float ps_a = 0.0f;
    for (int i = 0; i < 32; ++i) {
        if (i >= 30) asm volatile("s_waitcnt vmcnt(0)" ::: "memory");
        else         asm volatile("s_waitcnt vmcnt(2)" ::: "memory");
        SCHED();
        SBAR(); SCHED();
        if (i < 30) stageT(Qsrc + (long)((i + 2) * 64) * HID, HID, &QsA[((i + 2) % 3) * 4096]);

        f32x4 acc[4];
        #pragma unroll
        for (int x = 0; x < 4; x++)
            #pragma unroll
            for (int r = 0; r < 4; r++) acc[x][r] = 0.0f;

        const ush* Qb = &QsA[(i % 3) * 4096];
        __builtin_amdgcn_s_setprio(1);
        #pragma unroll
        for (int ks = 0; ks < 2; ks++) {
            const int uo = (ks ? (u0 ^ 4) : u0) * 8;
            short8 aq[4];
            #pragma unroll
            for (int mf = 0; mf < 4; mf++)
                aq[mf] = *reinterpret_cast<const short8*>(&Qb[(mf * 16 + l16) * 64 + uo]);
            #pragma unroll
            for (int mf = 0; mf < 4; mf++)
                acc[mf] = __builtin_amdgcn_mfma_f32_16x16x32_bf16(aq[mf], bk_a[ks], acc[mf], 0, 0, 0);
        }
        __builtin_amdgcn_s_setprio(0);

        #pragma unroll
        for (int mf = 0; mf < 4; mf++) {
            float s = 0.0f;
            #pragma unroll
            for (int r = 0; r < 4; r++) s += exp2f(acc[mf][r]);
            ps_a += s;
        }
    }
    float inv_a;
    {
        float v = ps_a;
        v += __shfl_xor(v, 16);
        v += __shfl_xor(v, 32);
        inv_a = 1.0f / v;
    }

    // ======== sweep 2: B(a) + denom(b) ========
    SBAR();
    stageT(Qsrc, HID, &QsA[0]);
    stageT(Vsrc, SEQ, VtA);
    stageT(Qsrc + (long)64 * HID, HID, &QsA[4096]);

    float ps_b = 0.0f;
    f32x4 octx[4];
    #pragma unroll
    for (int y = 0; y < 4; y++)
        #pragma unroll
        for (int r = 0; r < 4; r++) octx[y][r] = 0.0f;

    for (int i = 0; i < 32; ++i) {
        const int q0 = i << 6;
        if (i == 0) asm volatile("s_waitcnt vmcnt(0)" ::: "memory");
        else        asm volatile("s_waitcnt vmcnt(4)" ::: "memory");
        SCHED();
        SBAR(); SCHED();
        if (i < 30) stageT(Qsrc + (long)((i + 2) * 64) * HID, HID, &QsA[((i + 2) % 3) * 4096]);

        f32x4 aA[4], aB[4];
        #pragma unroll
        for (int x = 0; x < 4; x++)
            #pragma unroll
            for (int r = 0; r < 4; r++) { aA[x][r] = 0.0f; aB[x][r] = 0.0f; }

        const ush* Qb = &QsA[(i % 3) * 4096];
        __builtin_amdgcn_s_setprio(1);
        #pragma unroll
        for (int ks = 0; ks < 2; ks++) {
            const int uo = (ks ? (u0 ^ 4) : u0) * 8;
            short8 aq[4];
            #pragma unroll
            for (int mf = 0; mf < 4; mf++)
                aq[mf] = *reinterpret_cast<const short8*>(&Qb[(mf * 16 + l16) * 64 + uo]);
            #pragma unroll
            for (int mf = 0; mf < 4; mf++)
                aA[mf] = __builtin_amdgcn_mfma_f32_16x16x32_bf16(aq[mf], bk_a[ks], aA[mf], 0, 0, 0);
            #pragma unroll
            for (int mf = 0; mf < 4; mf++)
                aB[mf] = __builtin_amdgcn_mfma_f32_16x16x32_bf16(aq[mf], bk_b[ks], aB[mf], 0, 0, 0);
        }
        __builtin_amdgcn_s_setprio(0);

        // softmax(a) -> At (wave-private 16 rows)
        {
            const int krl = wv * 16 + l16;
            #pragma unroll
            for (int mf = 0; mf < 4; mf++) {
                const int qc = mf * 16 + lq * 4;
                float p0 = exp2f(aA[mf][0]) * inv_a;
                float p1 = exp2f(aA[mf][1]) * inv_a;
                float p2 = exp2f(aA[mf][2]) * inv_a;
                float p3 = exp2f(aA[mf][3]) * inv_a;
                unsigned int w0, w1;
                asm volatile("v_cvt_pk_bf16_f32 %0, %1, %2" : "=v"(w0) : "v"(p0), "v"(p1));
                asm volatile("v_cvt_pk_bf16_f32 %0, %1, %2" : "=v"(w1) : "v"(p2), "v"(p3));
                *reinterpret_cast<uint2*>(&At[krl][qc]) = make_uint2(w0, w1);
            }
        }
        asm volatile("s_waitcnt lgkmcnt(0)" ::: "memory");
        SCHED();

        uint2 wreg[4];
        #pragma unroll
        for (int j = 0; j < 4; ++j)
            wreg[j] = *reinterpret_cast<const uint2*>(&At[wv * 16 + j * 4 + rlo][qc2]);

        // PV(a)
        __builtin_amdgcn_s_setprio(1);
        #pragma unroll
        for (int ks = 0; ks < 2; ks++) {
            const int uo = (ks ? (u0 ^ 4) : u0) * 8;
            short8 a = *reinterpret_cast<const short8*>(&At[wv * 16 + l16][ks * 32 + lq * 8]);
            #pragma unroll
            for (int nf = 0; nf < 4; nf++) {
                short8 bv = *reinterpret_cast<const short8*>(&VtA[(nf * 16 + l16) * 64 + uo]);
                octx[nf] = __builtin_amdgcn_mfma_f32_16x16x32_bf16(a, bv, octx[nf], 0, 0, 0);
            }
        }
        __builtin_amdgcn_s_setprio(0);

        // denom(b)
        #pragma unroll
        for (int mf = 0; mf < 4; mf++) {
            float s = 0.0f;
            #pragma unroll
            for (int r = 0; r < 4; r++) s += exp2f(aB[mf][r]);
            ps_b += s;
        }

        SBAR(); SCHED();                     // all waves done reading VtA
        if (i < 31) stageT(Vsrc + (i + 1) * 64, SEQ, VtA);

        // attn(a) stores: 4 rows x 256B contiguous per instr, nontemporal
        #pragma unroll
        for (int j = 0; j < 4; ++j) {
            const int rl = rowbase_a + wv * 16 + j * 4 + rlo;
            f32x4 st;
            st[0] = __uint_as_float(wreg[j].x << 16);
            st[1] = __uint_as_float(wreg[j].x & 0xffff0000u);
            st[2] = __uint_as_float(wreg[j].y << 16);
            st[3] = __uint_as_float(wreg[j].y & 0xffff0000u);
            __builtin_nontemporal_store(st,
                reinterpret_cast<f32x4*>(attnp + ((long)bh * SEQ + rl) * SEQ + q0 + qc2));
        }
    }
    float inv_b;
    {
        float v = ps_b;
        v += __shfl_xor(v, 16);
        v += __shfl_xor(v, 32);
        inv_b = 1.0f / v;
    }

    // epilogue(a): out = gate * ctx
    #pragma unroll
    for (int nf = 0; nf < 4; nf++) {
        int col = colbase + nf * 16 + l16;
        #pragma unroll
        for (int r = 0; r < 4; r++) {
            long idx = (long)(tb + rowbase_a + wv * 16 + lq * 4 + r) * HID + col;
            float g = __builtin_nontemporal_load(&outp[idx]);
            __builtin_nontemporal_store(g * octx[nf][r], &outp[idx]);
        }
    }

    // ======== sweep 3: B(b) ========
    stageT(Qsrc, HID, &QsA[0]);
    stageT(Vsrc, SEQ, VtA);
    stageT(Qsrc + (long)64 * HID, HID, &QsA[4096]);

    #pragma unroll
    for (int y = 0; y < 4; y++)
        #pragma unroll
        for (int r = 0; r < 4; r++) octx[y][r] = 0.0f;

    for (int i = 0; i < 32; ++i) {
        const int q0 = i << 6;
        if (i == 0) asm volatile("s_waitcnt vmcnt(0)" ::: "memory");
        else        asm volatile("s_waitcnt vmcnt(4)" ::: "memory");
        SCHED();
        SBAR(); SCHED();
        if (i < 30) stageT(Qsrc + (long)((i + 2) * 64) * HID, HID, &QsA[((i + 2) % 3) * 4096]);

        f32x4 aB[4];
        #pragma unroll
        for (int x = 0; x < 4; x++)
            #pragma unroll
            for (int r = 0; r < 4; r++) aB[x][r] = 0.0f;

        const ush* Qb = &QsA[(i % 3) * 4096];
        __builtin_amdgcn_s_setprio(1);
        #pragma unroll
        for (int ks = 0; ks < 2; ks++) {
            const int uo = (ks ? (u0 ^ 4) : u0) * 8;
            short8 aq[4];
            #pragma unroll
            for (int mf = 0; mf < 4; mf++)
                aq[mf] = *reinterpret_cast<const short8*>(&Qb[(mf * 16 + l16) * 64 + uo]);
            #pragma unroll
            for (int mf = 0; mf < 4; mf++)
                aB[mf] = __builtin_amdgcn_mfma_f32_16x16x32_bf16(aq[mf], bk_b[ks], aB[mf], 0, 0, 0);
        }
        __builtin_amdgcn_s_setprio(0);

        {
            const int krl = wv * 16 + l16;
            #pragma unroll
            for (int mf = 0; mf < 4; mf++) {
                const int qc = mf * 16 + lq * 4;
                float p0 = exp2f(aB[mf][0]) * inv_b;
                float p1 = exp2f(aB[mf][1]) * inv_b;
                float p2 = exp2f(aB[mf][2]) * inv_b;
                float p3 = exp2f(aB[mf][3]) * inv_b;
                unsigned int w0, w1;
                asm volatile("v_cvt_pk_bf16_f32 %0, %1, %2" : "=v"(w0) : "v"(p0), "v"(p1));
                asm volatile("v_cvt_pk_bf16_f32 %0, %1, %2" : "=v"(w1) : "v"(p2), "v"(p3));
                *reinterpret_cast<uint2*>(&At[krl][qc]) = make_uint2(w0, w1);
            }
        }
        asm volatile("s_waitcnt lgkmcnt(0)" ::: "memory");
        SCHED();

        uint2 wreg[4];
        #pragma unroll
        for (int j = 0; j < 4; ++j)
            wreg[j] = *reinterpret_cast<const uint2*>(&At[wv * 16 + j * 4 + rlo][qc2]);

        __builtin_amdgcn_s_setprio(1);
        #pragma unroll
        for (int ks = 0; ks < 2; ks++) {
            const int uo = (ks ? (u0 ^ 4) : u0) * 8;
            short8 a = *reinterpret_cast<const short8*>(&At[wv * 16 + l16][ks * 32 + lq * 8]);
            #pragma unroll
            for (int nf = 0; nf < 4; nf++) {
                short8 bv = *reinterpret_cast<const short8*>(&VtA[(nf * 16 + l16) * 64 + uo]);
                octx[nf] = __builtin_amdgcn_mfma_f32_16x16x32_bf16(a, bv, octx[nf], 0, 0, 0);
            }
        }
        __builtin_amdgcn_s_setprio(0);

        SBAR(); SCHED();
        if (i < 31) stageT(Vsrc + (i + 1) * 64, SEQ, VtA);

        #pragma unroll
        for (int j = 0; j < 4; ++j) {
            const int rl = rowbase_b + wv * 16 + j * 4 + rlo;
            f32x4 st;
            st[0] = __uint_as_float(wreg[j].x << 16);
            st[1] = __uint_as_float(wreg[j].x & 0xffff0000u);
            st[2] = __uint_as_float(wreg[j].y << 16);
            st[3] = __uint_as_float(wreg[j].y & 0xffff0000u);
            __builtin_nontemporal_store(st,
                reinterpret_cast<f32x4*>(attnp + ((long)bh * SEQ + rl) * SEQ + q0 + qc2));
        }
    }

    // epilogue(b)
    #pragma unroll
    for (int nf = 0; nf < 4; nf++) {
        int col = colbase + nf * 16 + l16;
        #pragma unroll
        for (int r = 0; r < 4; r++) {
            long idx = (long)(tb + rowbase_b + wv * 16 + lq * 4 + r) * HID + col;
            float g = __builtin_nontemporal_load(&outp[idx]);
            __builtin_nontemporal_store(g * octx[nf][r], &outp[idx]);
        }
    }
}

extern "C" void kernel_launch(void* const* d_in, const int* in_sizes, int n_in,
                              void* d_out, int out_size, void* d_ws, size_t ws_size,
                              hipStream_t stream)
{
    const float* X  = (const float*)d_in[0];
    const float* Wq = (const float*)d_in[1];
    const float* Wk = (const float*)d_in[2];
    const float* Wg = (const float*)d_in[3];
    const float* bg = (const float*)d_in[4];

    float* outp  = (float*)d_out;
    float* attnp = outp + (long)NTOK * HID;

    ush* Qbf = (ush*)d_ws;
    ush* Kbf = Qbf + (long)NTOK * HID;
    ush* VtG = Kbf + (long)NTOK * HID;

    ush* Xbf = (ush*)(outp + 134742016L);
    ush* Wbf = Xbf + (long)NTOK * HID;

    cvt_kernel<<<3584, 256, 0, stream>>>(X, Wq, Wk, Wg, Xbf, Wbf);
    proj_kernel<<<dim3(24, 32), 256, 0, stream>>>(Xbf, Wbf, bg, Qbf, Kbf, VtG, outp);
    attn_kernel<<<512, 256, 0, stream>>>(Qbf, Kbf, VtG, outp, attnp);
}